// Round 14
// baseline (2136.383 us; speedup 1.0000x reference)
//
#include <hip/hip_runtime.h>

#define Nn 4096
#define Ff 256
#define NCLS 16
#define Ne 65536
#define TSZ 262144
#define NF (Nn*Ff)
#define NNx (Nn*Nn)

typedef unsigned short u16;
typedef unsigned int u32;
typedef __attribute__((ext_vector_type(8))) short short8;
typedef __attribute__((ext_vector_type(4))) float float4v;

__device__ __forceinline__ float bfh(u16 u){ return __uint_as_float(((u32)u)<<16); }
__device__ __forceinline__ u16 f2bf(float f){
    u32 u = __float_as_uint(f);
    return (u16)((u + 0x7FFFu + ((u>>16)&1u)) >> 16);
}
__device__ __forceinline__ void gload16(const u16* g, u16* l){
    __builtin_amdgcn_global_load_lds(
        (const __attribute__((address_space(1))) u32*)(const void*)g,
        (__attribute__((address_space(3))) u32*)(void*)l, 16, 0, 0);
}

// ---------------- device-global workspace ----------------
__device__ float g_yA[NF], g_yB[NF], g_zA[NF], g_zB[NF], g_t1[NF], g_T1[NF];
__device__ float g_Gp[32*Ff*Ff], g_col[Ff], g_P[Ne], g_cc[Ne], g_hV[TSZ];
__device__ float g_pb[(size_t)24*NF];
__device__ u32 g_hK[TSZ], g_slot[Ne];
__device__ int g_cntI[Nn], g_cntJ[Nn], g_rpI[Nn+1], g_rpJ[Nn+1], g_fI[Nn], g_fJ[Nn];
__device__ int g_lI[Ne], g_lJ[Ne];
__device__ __align__(16) u16 g_w1h[NNx], g_w1l[NNx];
__device__ __align__(16) u16 g_meh[NNx], g_mel[NNx];
__device__ __align__(16) u16 g_mth[NNx], g_mtl[NNx];
__device__ __align__(16) u16 g_x0h[NF], g_x0l[NF], g_x1h[NF], g_x1l[NF];     // y^T splits (dbuf)
__device__ __align__(16) u16 g_zt0h[NF], g_zt0l[NF], g_zt1h[NF], g_zt1l[NF]; // z^T splits (dbuf)
__device__ __align__(16) u16 g_yr0h[NF], g_yr0l[NF], g_yr1h[NF], g_yr1l[NF]; // y row splits (dbuf)
__device__ __align__(16) u16 g_tth[NF], g_ttl[NF];                           // t1^T split
__device__ __align__(16) u16 g_gth[Ff*Ff], g_gtl[Ff*Ff];
__device__ __align__(16) u16 g_g2h[Ff*Ff], g_g2l[Ff*Ff];                     // next-layer G prefetch

// ---------------- utility ----------------
__global__ __launch_bounds__(256) void k_zero(float* p, int n){
    int i = blockIdx.x*256 + threadIdx.x;
    if (i < n) p[i] = 0.f;
}
__global__ __launch_bounds__(256) void k_zeroi(int* p, int n){
    int i = blockIdx.x*256 + threadIdx.x;
    if (i < n) p[i] = 0;
}
__global__ __launch_bounds__(256) void k_fillc(float* p, float v, int n){
    int i = blockIdx.x*256 + threadIdx.x;
    if (i < n) p[i] = v;
}
__global__ __launch_bounds__(256) void k_hkeys_clear(u32* K){
    int i = blockIdx.x*256 + threadIdx.x;
    if (i < TSZ) K[i] = 0xFFFFFFFFu;
}
__global__ __launch_bounds__(256) void k_hsetup(u32* K, u32* slot, const int* ei, const int* ej){
    int e = blockIdx.x*256 + threadIdx.x;
    if (e >= Ne) return;
    u32 key = ((u32)ei[e] << 12) | (u32)ej[e];
    u32 h = (key * 2654435761u) & (TSZ-1);
    for (;;){
        u32 old = atomicCAS(&K[h], 0xFFFFFFFFu, key);
        if (old == 0xFFFFFFFFu || old == key){ slot[e] = h; break; }
        h = (h+1) & (TSZ-1);
    }
}

// ---------------- CSR build ----------------
__global__ __launch_bounds__(256) void k_count(int* cntI, int* cntJ, const int* ei, const int* ej){
    int e = blockIdx.x*256 + threadIdx.x;
    if (e < Ne){ atomicAdd(&cntI[ei[e]], 1); atomicAdd(&cntJ[ej[e]], 1); }
}
__global__ __launch_bounds__(1024) void k_scan(const int* cnt, int* rp){
    __shared__ int s[1024];
    int t = threadIdx.x, b = t*4;
    int a0 = cnt[b], a1 = cnt[b+1], a2 = cnt[b+2], a3 = cnt[b+3];
    int sum = a0+a1+a2+a3;
    s[t] = sum; __syncthreads();
    for (int o = 1; o < 1024; o <<= 1){
        int v = (t >= o) ? s[t-o] : 0;
        __syncthreads();
        s[t] += v;
        __syncthreads();
    }
    int excl = s[t] - sum;
    rp[b] = excl; rp[b+1] = excl+a0; rp[b+2] = excl+a0+a1; rp[b+3] = excl+a0+a1+a2;
    if (t == 1023) rp[4096] = s[1023];
}
__global__ __launch_bounds__(256) void k_fillcsr(const int* rpI, const int* rpJ, int* fI, int* fJ,
                                                 int* lI, int* lJ, const int* ei, const int* ej){
    int e = blockIdx.x*256 + threadIdx.x;
    if (e >= Ne) return;
    int i = ei[e], j = ej[e];
    lI[rpI[i] + atomicAdd(&fI[i], 1)] = e;
    lJ[rpJ[j] + atomicAdd(&fJ[j], 1)] = e;
}

// ---------------- split precompute ----------------
__global__ __launch_bounds__(256) void k_split4(ushort4* hi, ushort4* lo, const float4* w, int n4){
    int i = blockIdx.x*256 + threadIdx.x;
    if (i >= n4) return;
    float4 v = w[i];
    ushort4 h, l;
    h.x = f2bf(v.x); l.x = f2bf(v.x - bfh(h.x));
    h.y = f2bf(v.y); l.y = f2bf(v.y - bfh(h.y));
    h.z = f2bf(v.z); l.z = f2bf(v.z - bfh(h.z));
    h.w = f2bf(v.w); l.w = f2bf(v.w - bfh(h.w));
    hi[i] = h; lo[i] = l;
}
// fused mEA (row-major) + mEA^T split — r6 scalar version (HBM-roofline, 0 conflicts)
__global__ __launch_bounds__(256) void k_splitME2(u16* meh, u16* mel, u16* mth, u16* mtl,
                                                  const float* ea, const float* w22){
    __shared__ float T[64][65];
    int r0 = blockIdx.y*64, c0 = blockIdx.x*64;
    int c = threadIdx.x & 63, rr = threadIdx.x >> 6;
    for (int q = 0; q < 16; ++q){
        int r = q*4 + rr;
        size_t idx = (size_t)(r0+r)*Nn + c0 + c;
        float v = 0.5f*ea[idx]*w22[idx];
        T[r][c] = v;
        u16 h = f2bf(v); meh[idx] = h; mel[idx] = f2bf(v - bfh(h));
    }
    __syncthreads();
    for (int q = 0; q < 16; ++q){
        int r = q*4 + rr;
        float v = T[c][r];
        size_t o = (size_t)(c0+r)*Nn + r0 + c;
        u16 h = f2bf(v); mth[o] = h; mtl[o] = f2bf(v - bfh(h));
    }
}
// X [4096][256] f32 -> X^T split [256][4096]
__global__ __launch_bounds__(256) void k_splitXT(u16* hi, u16* lo, const float* X){
    __shared__ float T[64][65];
    int r0 = blockIdx.y*64, c0 = blockIdx.x*64;
    int c = threadIdx.x & 63, rr = threadIdx.x >> 6;
    for (int q = 0; q < 16; ++q){
        int r = q*4 + rr;
        T[r][c] = X[(size_t)(r0+r)*Ff + c0 + c];
    }
    __syncthreads();
    for (int q = 0; q < 16; ++q){
        int r = q*4 + rr;
        float v = T[c][r];
        size_t o = (size_t)(c0+r)*Nn + r0 + c;
        u16 h = f2bf(v); hi[o] = h; lo[o] = f2bf(v - bfh(h));
    }
}
// sum 16 G-planes (base 0) -> G^T split
__global__ __launch_bounds__(256) void k_splitGT(u16* hi, u16* lo, const float* Gp){
    __shared__ float T[64][65];
    int r0 = blockIdx.y*64, c0 = blockIdx.x*64;
    int c = threadIdx.x & 63, rr = threadIdx.x >> 6;
    for (int q = 0; q < 16; ++q){
        int r = q*4 + rr;
        float v = 0.f;
        #pragma unroll
        for (int z = 0; z < 16; ++z) v += Gp[z*(Ff*Ff) + (r0+r)*Ff + c0 + c];
        T[r][c] = v;
    }
    __syncthreads();
    for (int q = 0; q < 16; ++q){
        int r = q*4 + rr;
        float v = T[c][r];
        int o = (c0+r)*Ff + r0 + c;
        u16 h = f2bf(v); hi[o] = h; lo[o] = f2bf(v - bfh(h));
    }
}
// batched: z=0 -> planes 0..15 -> (h0,l0); z=1 -> planes 16..31 -> (h1,l1)
__global__ __launch_bounds__(256) void k_splitGT2(u16* h0, u16* l0, u16* h1, u16* l1,
                                                  const float* Gp){
    __shared__ float T[64][65];
    const int which = blockIdx.z;
    u16* hi = which ? h1 : h0;
    u16* lo = which ? l1 : l0;
    const float* G = Gp + (size_t)which*16*(Ff*Ff);
    int r0 = blockIdx.y*64, c0 = blockIdx.x*64;
    int c = threadIdx.x & 63, rr = threadIdx.x >> 6;
    for (int q = 0; q < 16; ++q){
        int r = q*4 + rr;
        float v = 0.f;
        #pragma unroll
        for (int z = 0; z < 16; ++z) v += G[z*(Ff*Ff) + (r0+r)*Ff + c0 + c];
        T[r][c] = v;
    }
    __syncthreads();
    for (int q = 0; q < 16; ++q){
        int r = q*4 + rr;
        float v = T[c][r];
        int o = (c0+r)*Ff + r0 + c;
        u16 h = f2bf(v); hi[o] = h; lo[o] = f2bf(v - bfh(h));
    }
}

// ---------------- small-GEMM MFMA tile core (verified r5-r12) ----------------
__device__ __forceinline__ void mm_tile(
    const u16* __restrict__ Ahp, const u16* __restrict__ Alp,
    const u16* __restrict__ Bhp, const u16* __restrict__ Blp,
    size_t sA, size_t sB, int i0, int j0, int k0,
    u16* LAh, u16* LAl, u16* LBh, u16* LBl,
    float4v* acc, int lane, int w)
{
    const int g1 = w*64 + lane;
    const int g2 = g1 + 256;
    const int r1 = g1>>3, p1 = g1&7, r2 = g2>>3, p2 = g2&7;
    const size_t a1 = (size_t)(i0+r1)*sA + (size_t)(k0 + ((p1 ^ (r1&7))<<3));
    const size_t a2 = (size_t)(i0+r2)*sA + (size_t)(k0 + ((p2 ^ (r2&7))<<3));
    const size_t b1 = (size_t)(j0+r1)*sB + (size_t)(k0 + ((p1 ^ (r1&7))<<3));
    const size_t b2 = (size_t)(j0+r2)*sB + (size_t)(k0 + ((p2 ^ (r2&7))<<3));
    __syncthreads();
    gload16(Ahp + a1, LAh + g1*8);
    gload16(Ahp + a2, LAh + g2*8);
    gload16(Alp + a1, LAl + g1*8);
    gload16(Alp + a2, LAl + g2*8);
    gload16(Bhp + b1, LBh + g1*8);
    gload16(Bhp + b2, LBh + g2*8);
    gload16(Blp + b1, LBl + g1*8);
    gload16(Blp + b2, LBl + g2*8);
    __syncthreads();
    const int arow = w*16 + (lane&15);
    const int aswz = arow & 7;
    #pragma unroll
    for (int kk = 0; kk < 2; ++kk){
        const int ch = kk*4 + (lane>>4);
        short8 ah = *(const short8*)(LAh + arow*64 + ((ch ^ aswz)<<3));
        short8 al = *(const short8*)(LAl + arow*64 + ((ch ^ aswz)<<3));
        #pragma unroll
        for (int c = 0; c < 4; ++c){
            const int brow = c*16 + (lane&15);
            const int bo = brow*64 + ((ch ^ (brow&7))<<3);
            short8 bh = *(const short8*)(LBh + bo);
            short8 bl = *(const short8*)(LBl + bo);
            acc[c] = __builtin_amdgcn_mfma_f32_16x16x32_bf16(ah, bh, acc[c], 0,0,0);
            acc[c] = __builtin_amdgcn_mfma_f32_16x16x32_bf16(ah, bl, acc[c], 0,0,0);
            acc[c] = __builtin_amdgcn_mfma_f32_16x16x32_bf16(al, bh, acc[c], 0,0,0);
        }
    }
}

// small GEMM (K=256): V3: out=aux-acc  V4: out=aux[col]-acc  V5: out=acc
template<int V>
__global__ __launch_bounds__(256) void k_mm(float* __restrict__ out,
        const u16* __restrict__ Ahp, const u16* __restrict__ Alp,
        const u16* __restrict__ Bhp, const u16* __restrict__ Blp,
        const float* __restrict__ aux1){
    __shared__ u16 LAh[4096], LAl[4096], LBh[4096], LBl[4096];
    const int tid = threadIdx.x, lane = tid & 63, w = tid >> 6;
    const int j0 = blockIdx.x*64, i0 = blockIdx.y*64;
    float4v acc[4];
    #pragma unroll
    for (int c = 0; c < 4; ++c) acc[c] = (float4v){0.f,0.f,0.f,0.f};
    for (int kt = 0; kt < 4; ++kt)
        mm_tile(Ahp, Alp, Bhp, Blp, (size_t)Ff, (size_t)Ff, i0, j0, kt*64, LAh, LAl, LBh, LBl, acc, lane, w);
    #pragma unroll
    for (int c = 0; c < 4; ++c)
        #pragma unroll
        for (int r = 0; r < 4; ++r){
            int grow = i0 + w*16 + (lane>>4)*4 + r;
            int gcol = j0 + c*16 + (lane&15);
            size_t idx = (size_t)grow*Ff + gcol;
            float v = acc[c][r];
            if constexpr (V == 3) out[idx] = aux1[idx] - v;
            if constexpr (V == 4) out[idx] = aux1[gcol] - v;
            if constexpr (V == 5) out[idx] = v;
        }
}

// Gram GEMM (single): Gp[z] = partial over K-chunk
__global__ __launch_bounds__(256) void k_gram_mm(float* __restrict__ Gp,
        const u16* __restrict__ Ahp, const u16* __restrict__ Alp,
        const u16* __restrict__ Bhp, const u16* __restrict__ Blp){
    __shared__ u16 LAh[4096], LAl[4096], LBh[4096], LBl[4096];
    const int tid = threadIdx.x, lane = tid & 63, w = tid >> 6;
    const int j0 = blockIdx.x*64, i0 = blockIdx.y*64, kb = blockIdx.z*256;
    float4v acc[4];
    #pragma unroll
    for (int c = 0; c < 4; ++c) acc[c] = (float4v){0.f,0.f,0.f,0.f};
    for (int kt = 0; kt < 4; ++kt)
        mm_tile(Ahp, Alp, Bhp, Blp, (size_t)Nn, (size_t)Nn, i0, j0, kb + kt*64, LAh, LAl, LBh, LBl, acc, lane, w);
    float* op = Gp + (size_t)blockIdx.z*(Ff*Ff);
    #pragma unroll
    for (int c = 0; c < 4; ++c)
        #pragma unroll
        for (int r = 0; r < 4; ++r){
            int grow = i0 + w*16 + (lane>>4)*4 + r;
            int gcol = j0 + c*16 + (lane&15);
            op[grow*Ff + gcol] = acc[c][r];
        }
}

// Batched Gram: z=0..15 -> (A,B) pair [y_old^T y_new]; z=16..31 -> (B,B) [y_new^T y_new]
__global__ __launch_bounds__(256) void k_gram_mm2(float* __restrict__ Gp,
        const u16* __restrict__ Ahp, const u16* __restrict__ Alp,
        const u16* __restrict__ Bhp, const u16* __restrict__ Blp){
    __shared__ u16 LAh[4096], LAl[4096], LBh[4096], LBl[4096];
    const int tid = threadIdx.x, lane = tid & 63, w = tid >> 6;
    const int j0 = blockIdx.x*64, i0 = blockIdx.y*64;
    const int pz = blockIdx.z;
    const int kb = (pz & 15)*256, which = pz >> 4;
    const u16* pAh = which ? Bhp : Ahp;
    const u16* pAl = which ? Blp : Alp;
    float4v acc[4];
    #pragma unroll
    for (int c = 0; c < 4; ++c) acc[c] = (float4v){0.f,0.f,0.f,0.f};
    for (int kt = 0; kt < 4; ++kt)
        mm_tile(pAh, pAl, Bhp, Blp, (size_t)Nn, (size_t)Nn, i0, j0, kb + kt*64, LAh, LAl, LBh, LBl, acc, lane, w);
    float* op = Gp + (size_t)pz*(Ff*Ff);
    #pragma unroll
    for (int c = 0; c < 4; ++c)
        #pragma unroll
        for (int r = 0; r < 4; ++r){
            int grow = i0 + w*16 + (lane>>4)*4 + r;
            int gcol = j0 + c*16 + (lane&15);
            op[grow*Ff + gcol] = acc[c][r];
        }
}

// ---------------- big GEMM (r12-verified core, templated K-split) ----------------
// BM=64, BN=256, BK=64, 512 thr, 80 KB LDS -> 2 blocks/CU.
// grid: (KSP, 64, nb): x = K-plane, y = i-block, z = batch. 64/KSP kt per block.
template<int KSP>
__global__ __launch_bounds__(512) void k_mmB(float* __restrict__ pb,
        const u16* __restrict__ A0h, const u16* __restrict__ A0l,
        const u16* __restrict__ B0h, const u16* __restrict__ B0l,
        const u16* __restrict__ A1h, const u16* __restrict__ A1l,
        const u16* __restrict__ B1h, const u16* __restrict__ B1l,
        const u16* __restrict__ A2h, const u16* __restrict__ A2l,
        const u16* __restrict__ B2h, const u16* __restrict__ B2l){
    __shared__ u16 LAh[4096], LAl[4096], LBh[16384], LBl[16384];
    const int tid = threadIdx.x, lane = tid & 63, w = tid >> 6;
    const int z = blockIdx.x, i0 = blockIdx.y*64, bat = blockIdx.z;
    const u16 *Ah, *Al, *Bh, *Bl;
    if (bat == 0){ Ah = A0h; Al = A0l; Bh = B0h; Bl = B0l; }
    else if (bat == 1){ Ah = A1h; Al = A1l; Bh = B1h; Bl = B1l; }
    else { Ah = A2h; Al = A2l; Bh = B2h; Bl = B2l; }
    const int wr = w >> 2, wc = w & 3;
    float4v acc[2][4];
    #pragma unroll
    for (int m = 0; m < 2; ++m)
        #pragma unroll
        for (int n = 0; n < 4; ++n) acc[m][n] = (float4v){0.f,0.f,0.f,0.f};

    const int ra = tid >> 3, pa = tid & 7;
    const size_t aoff = (size_t)(i0+ra)*Nn + (size_t)((pa ^ (ra&7))<<3);
    constexpr int NKT = 64 / KSP;

    for (int kt = 0; kt < NKT; ++kt){
        const int k0 = z*(NKT*64) + kt*64;
        __syncthreads();
        gload16(Ah + aoff + k0, LAh + tid*8);
        gload16(Al + aoff + k0, LAl + tid*8);
        #pragma unroll
        for (int it = 0; it < 4; ++it){
            int g = it*512 + tid;
            int r = g >> 3, p = g & 7;
            size_t b = (size_t)r*Nn + (size_t)(k0 + ((p ^ (r&7))<<3));
            gload16(Bh + b, LBh + g*8);
            gload16(Bl + b, LBl + g*8);
        }
        __syncthreads();
        #pragma unroll
        for (int kk = 0; kk < 2; ++kk){
            const int ch = kk*4 + (lane>>4);
            short8 ah0, ah1, al0, al1;
            {
                const int arow = wr*32 + (lane&15);
                const int ao = arow*64 + ((ch ^ (arow&7))<<3);
                ah0 = *(const short8*)(LAh + ao);
                al0 = *(const short8*)(LAl + ao);
            }
            {
                const int arow = wr*32 + 16 + (lane&15);
                const int ao = arow*64 + ((ch ^ (arow&7))<<3);
                ah1 = *(const short8*)(LAh + ao);
                al1 = *(const short8*)(LAl + ao);
            }
            #pragma unroll
            for (int n = 0; n < 4; ++n){
                const int bcol = wc*64 + n*16 + (lane&15);
                const int bo = bcol*64 + ((ch ^ (bcol&7))<<3);
                short8 bh = *(const short8*)(LBh + bo);
                short8 bl = *(const short8*)(LBl + bo);
                acc[0][n] = __builtin_amdgcn_mfma_f32_16x16x32_bf16(ah0, bh, acc[0][n], 0,0,0);
                acc[0][n] = __builtin_amdgcn_mfma_f32_16x16x32_bf16(ah0, bl, acc[0][n], 0,0,0);
                acc[0][n] = __builtin_amdgcn_mfma_f32_16x16x32_bf16(al0, bh, acc[0][n], 0,0,0);
                acc[1][n] = __builtin_amdgcn_mfma_f32_16x16x32_bf16(ah1, bh, acc[1][n], 0,0,0);
                acc[1][n] = __builtin_amdgcn_mfma_f32_16x16x32_bf16(ah1, bl, acc[1][n], 0,0,0);
                acc[1][n] = __builtin_amdgcn_mfma_f32_16x16x32_bf16(al1, bh, acc[1][n], 0,0,0);
            }
        }
    }
    float* op = pb + ((size_t)bat*KSP + z)*NF;
    #pragma unroll
    for (int m = 0; m < 2; ++m)
        #pragma unroll
        for (int n = 0; n < 4; ++n)
            #pragma unroll
            for (int r = 0; r < 4; ++r){
                int row = i0 + wr*32 + m*16 + (lane>>4)*4 + r;
                int col = wc*64 + n*16 + (lane&15);
                op[(size_t)row*Ff + col] = acc[m][n][r];
            }
}

// ---- fused CSR + plane-reduce + t1 finish + transpose-split + zn  (merges r12 steps 4+5) ----
// t1v = t1_base[idx] + CSR_T + sum(pb[0..3]) - (HASM? sum(pb[8..11]) : 0)
// zn  = z[idx] - sum(pb[4..7]) - CSR_Z ;   tth/ttl = transpose-split(t1v)
template<int HASM>
__global__ __launch_bounds__(256) void k_csrRed(const float* __restrict__ t1b, float* __restrict__ zn,
        const float* __restrict__ y, const float* __restrict__ z, const float* __restrict__ pb,
        const float* __restrict__ cc, const float* __restrict__ P,
        const int* __restrict__ rpI, const int* __restrict__ lI, const int* __restrict__ ej,
        const int* __restrict__ rpJ, const int* __restrict__ lJ, const int* __restrict__ ei,
        u16* __restrict__ th, u16* __restrict__ tl){
    __shared__ float T[64][65];
    const int c0 = blockIdx.x*64, r0 = blockIdx.y*64;
    const int c = threadIdx.x & 63, rr = threadIdx.x >> 6;
    for (int q = 0; q < 16; ++q){
        int row = r0 + q*4 + rr;
        size_t idx = (size_t)row*Ff + c0 + c;
        float s0 = 0.f, sz = 0.f;
        #pragma unroll
        for (int p = 0; p < 4; ++p) s0 += pb[(size_t)p*NF + idx];
        #pragma unroll
        for (int p = 4; p < 8; ++p) sz += pb[(size_t)p*NF + idx];
        if constexpr (HASM){
            #pragma unroll
            for (int p = 8; p < 12; ++p) s0 -= pb[(size_t)p*NF + idx];
        }
        float at = 0.f, az = 0.f;
        const int b0 = rpI[row], b1 = rpI[row+1];
        for (int p = b0; p < b1; ++p){
            int e = lI[p];
            float ce = cc[e];
            int j = ej[e];
            at += ce * y[(size_t)j*Ff + c0 + c];
            az += ce * z[(size_t)j*Ff + c0 + c];
        }
        if constexpr (HASM){
            const int d0 = rpJ[row], d1 = rpJ[row+1];
            for (int p = d0; p < d1; ++p){
                int e = lJ[p];
                at -= 0.5f * P[e] * y[(size_t)ei[e]*Ff + c0 + c];
            }
        }
        float val = t1b[idx] + at + s0;
        T[q*4+rr][c] = val;
        zn[idx] = z[idx] - sz - az;
    }
    __syncthreads();
    for (int q = 0; q < 16; ++q){
        int r = q*4 + rr;
        float v = T[c][r];
        size_t o = (size_t)(c0+r)*Nn + r0 + c;
        u16 h = f2bf(v); th[o] = h; tl[o] = f2bf(v - bfh(h));
    }
}

// yn epilogue (w1 uses KSP=8): yn = feat + 0.5*sigmoid(sum(pb[0..7])); row + transpose splits
__global__ __launch_bounds__(256) void k_redY(float* __restrict__ yn, const float* __restrict__ pb,
        const float* __restrict__ feat, u16* __restrict__ rh, u16* __restrict__ rl,
        u16* __restrict__ th, u16* __restrict__ tl){
    __shared__ float T[64][65];
    const int c0 = blockIdx.x*64, r0 = blockIdx.y*64;
    const int c = threadIdx.x & 63, rr = threadIdx.x >> 6;
    for (int q = 0; q < 16; ++q){
        int row = q*4 + rr;
        size_t idx = (size_t)(r0+row)*Ff + c0 + c;
        float s = 0.f;
        #pragma unroll
        for (int p = 0; p < 8; ++p) s += pb[(size_t)p*NF + idx];
        float val = feat[idx] + 0.5f*(1.f/(1.f+expf(-s)));
        yn[idx] = val;
        u16 h = f2bf(val); rh[idx] = h; rl[idx] = f2bf(val - bfh(h));
        T[row][c] = val;
    }
    __syncthreads();
    for (int q = 0; q < 16; ++q){
        int r = q*4 + rr;
        float v = T[c][r];
        size_t o = (size_t)(c0+r)*Nn + r0 + c;
        u16 h = f2bf(v); th[o] = h; tl[o] = f2bf(v - bfh(h));
    }
}

__global__ __launch_bounds__(256) void k_colsum(float* col, const float* __restrict__ y){
    int j = threadIdx.x;
    int r0 = blockIdx.x*64;
    float s = 0.f;
    for (int i = 0; i < 64; ++i) s += y[(size_t)(r0+i)*Ff + j];
    atomicAdd(&col[j], s);
}

// ---------------- per-edge kernels ----------------
__global__ __launch_bounds__(256) void k_pacc(float* __restrict__ P, float* __restrict__ hV,
        const float* __restrict__ z, const int* __restrict__ ei, const int* __restrict__ ej,
        const float* __restrict__ ev, const u32* __restrict__ slot){
    int e = blockIdx.x*4 + (threadIdx.x >> 6);
    int lane = threadIdx.x & 63;
    int i = ei[e], j = ej[e];
    float s = 0.f;
    #pragma unroll
    for (int q = 0; q < 4; ++q){
        int f = lane + q*64;
        float d = z[(size_t)i*Ff + f] - z[(size_t)j*Ff + f];
        s += d*d;
    }
    #pragma unroll
    for (int o = 32; o; o >>= 1) s += __shfl_xor(s, o);
    if (lane == 0){
        float v = sqrtf(s) * ev[e];
        P[e] = v;
        atomicAdd(&hV[slot[e]], v);
    }
}
__global__ __launch_bounds__(256) void k_ep(float* __restrict__ c, const float* __restrict__ y,
        const int* __restrict__ ei, const int* __restrict__ ej, const float* __restrict__ ev,
        const float* __restrict__ V, const u32* __restrict__ slot){
    int e = blockIdx.x*4 + (threadIdx.x >> 6);
    int lane = threadIdx.x & 63;
    int i = ei[e], j = ej[e];
    float s = 0.f;
    #pragma unroll
    for (int q = 0; q < 4; ++q){
        int f = lane + q*64;
        s += y[(size_t)i*Ff + f] * y[(size_t)j*Ff + f];
    }
    #pragma unroll
    for (int o = 32; o; o >>= 1) s += __shfl_xor(s, o);
    if (lane == 0) c[e] = ev[e] * (s - 0.5f * V[slot[e]]);
}

// ---------------- head ----------------
__global__ __launch_bounds__(256) void k_head(float* __restrict__ out, const float* __restrict__ y,
                                              const float* __restrict__ z, const float* __restrict__ w2w,
                                              const float* __restrict__ w2b){
    const int node = blockIdx.x, t = threadIdx.x;
    float yv = y[(size_t)node*Ff + t], zv = z[(size_t)node*Ff + t];
    float yc = fminf(fmaxf(yv, -1e37f), 1e37f);
    float zc = fminf(fmaxf(zv, -1e37f), 1e37f);
    __shared__ float sy[256], sz[256];
    sy[t] = fabsf(yc); sz[t] = fabsf(zc);
    __syncthreads();
    for (int s = 128; s; s >>= 1){ if (t < s){ sy[t]=fmaxf(sy[t],sy[t+s]); sz[t]=fmaxf(sz[t],sz[t+s]); } __syncthreads(); }
    float my_ = fmaxf(sy[0], 1e-30f), mz_ = fmaxf(sz[0], 1e-30f);
    __syncthreads();
    float ysc = yc/my_, zsc = zc/mz_;
    sy[t] = ysc*ysc; sz[t] = zsc*zsc;
    __syncthreads();
    for (int s = 128; s; s >>= 1){ if (t < s){ sy[t]+=sy[t+s]; sz[t]+=sz[t+s]; } __syncthreads(); }
    float ny = fmaxf(my_*sqrtf(sy[0]), 1e-12f);
    float nz = fmaxf(mz_*sqrtf(sz[0]), 1e-12f);
    float ynv = yc/ny, znv = zc/nz;
    float acc[NCLS];
    #pragma unroll
    for (int cc = 0; cc < NCLS; ++cc)
        acc[cc] = znv*w2w[t*NCLS+cc] + ynv*w2w[(Ff+t)*NCLS+cc];
    __shared__ float red[NCLS][257];
    #pragma unroll
    for (int cc = 0; cc < NCLS; ++cc) red[cc][t] = acc[cc];
    __syncthreads();
    for (int s = 128; s; s >>= 1){
        if (t < s){
            #pragma unroll
            for (int cc = 0; cc < NCLS; ++cc) red[cc][t] += red[cc][t+s];
        }
        __syncthreads();
    }
    __shared__ float lg[NCLS];
    __shared__ float ml[2];
    if (t < NCLS) lg[t] = red[t][0] + w2b[t];
    __syncthreads();
    if (t == 0){
        float m = -1e30f;
        for (int cc = 0; cc < NCLS; ++cc) m = fmaxf(m, lg[cc]);
        float se = 0.f;
        for (int cc = 0; cc < NCLS; ++cc) se += expf(lg[cc]-m);
        ml[0] = m; ml[1] = logf(se);
    }
    __syncthreads();
    if (t < NCLS) out[(size_t)node*NCLS + t] = lg[t] - ml[0] - ml[1];
}

extern "C" void kernel_launch(void* const* d_in, const int* in_sizes, int n_in,
                              void* d_out, int out_size, void* d_ws, size_t ws_size,
                              hipStream_t stream){
    const float* feat = (const float*)d_in[0];
    const float* z0i  = (const float*)d_in[1];
    const float* w1p  = (const float*)d_in[2];
    const float* EAp  = (const float*)d_in[3];
    const float* w2w  = (const float*)d_in[4];
    const float* w2b  = (const float*)d_in[5];
    const float* w22p = (const float*)d_in[7];
    const float* evp  = (const float*)d_in[8];
    const int* ei   = (const int*)d_in[9];
    const int* ej   = (const int*)d_in[10];
    float* out = (float*)d_out;

    int ok = (n_in == 11) && (out_size == Nn*NCLS)
           && in_sizes[0]==NF && in_sizes[1]==NF && in_sizes[2]==NNx && in_sizes[3]==NNx
           && in_sizes[4]==2*Ff*NCLS && in_sizes[5]==NCLS && in_sizes[6]==NNx && in_sizes[7]==NNx
           && in_sizes[8]==Ne && in_sizes[9]==Ne && in_sizes[10]==Ne;
    if (!ok){
        k_fillc<<<(out_size+255)/256, 256, 0, stream>>>(out, -100.0f, out_size);
        return;
    }

    float *yA,*yB,*zA,*zB,*t1,*T1,*Gp,*col,*P,*cc,*hV,*pb; u32 *hK,*slot;
    int *cntI,*cntJ,*rpI,*rpJ,*fI,*fJ,*lI,*lJ;
    u16 *w1h,*w1l,*meh,*mel,*mth,*mtl,*gth,*gtl,*g2h,*g2l,*tth,*ttl;
    u16 *xh[2],*xl[2],*zth[2],*ztl[2],*yrh[2],*yrl[2];
    hipGetSymbolAddress((void**)&yA,  HIP_SYMBOL(g_yA));
    hipGetSymbolAddress((void**)&yB,  HIP_SYMBOL(g_yB));
    hipGetSymbolAddress((void**)&zA,  HIP_SYMBOL(g_zA));
    hipGetSymbolAddress((void**)&zB,  HIP_SYMBOL(g_zB));
    hipGetSymbolAddress((void**)&t1,  HIP_SYMBOL(g_t1));
    hipGetSymbolAddress((void**)&T1,  HIP_SYMBOL(g_T1));
    hipGetSymbolAddress((void**)&Gp,  HIP_SYMBOL(g_Gp));
    hipGetSymbolAddress((void**)&col, HIP_SYMBOL(g_col));
    hipGetSymbolAddress((void**)&P,   HIP_SYMBOL(g_P));
    hipGetSymbolAddress((void**)&cc,  HIP_SYMBOL(g_cc));
    hipGetSymbolAddress((void**)&hV,  HIP_SYMBOL(g_hV));
    hipGetSymbolAddress((void**)&pb,  HIP_SYMBOL(g_pb));
    hipGetSymbolAddress((void**)&hK,  HIP_SYMBOL(g_hK));
    hipGetSymbolAddress((void**)&slot,HIP_SYMBOL(g_slot));
    hipGetSymbolAddress((void**)&cntI,HIP_SYMBOL(g_cntI));
    hipGetSymbolAddress((void**)&cntJ,HIP_SYMBOL(g_cntJ));
    hipGetSymbolAddress((void**)&rpI, HIP_SYMBOL(g_rpI));
    hipGetSymbolAddress((void**)&rpJ, HIP_SYMBOL(g_rpJ));
    hipGetSymbolAddress((void**)&fI,  HIP_SYMBOL(g_fI));
    hipGetSymbolAddress((void**)&fJ,  HIP_SYMBOL(g_fJ));
    hipGetSymbolAddress((void**)&lI,  HIP_SYMBOL(g_lI));
    hipGetSymbolAddress((void**)&lJ,  HIP_SYMBOL(g_lJ));
    hipGetSymbolAddress((void**)&w1h, HIP_SYMBOL(g_w1h));
    hipGetSymbolAddress((void**)&w1l, HIP_SYMBOL(g_w1l));
    hipGetSymbolAddress((void**)&meh, HIP_SYMBOL(g_meh));
    hipGetSymbolAddress((void**)&mel, HIP_SYMBOL(g_mel));
    hipGetSymbolAddress((void**)&mth, HIP_SYMBOL(g_mth));
    hipGetSymbolAddress((void**)&mtl, HIP_SYMBOL(g_mtl));
    hipGetSymbolAddress((void**)&gth, HIP_SYMBOL(g_gth));
    hipGetSymbolAddress((void**)&gtl, HIP_SYMBOL(g_gtl));
    hipGetSymbolAddress((void**)&g2h, HIP_SYMBOL(g_g2h));
    hipGetSymbolAddress((void**)&g2l, HIP_SYMBOL(g_g2l));
    hipGetSymbolAddress((void**)&tth, HIP_SYMBOL(g_tth));
    hipGetSymbolAddress((void**)&ttl, HIP_SYMBOL(g_ttl));
    hipGetSymbolAddress((void**)&xh[0], HIP_SYMBOL(g_x0h));
    hipGetSymbolAddress((void**)&xl[0], HIP_SYMBOL(g_x0l));
    hipGetSymbolAddress((void**)&xh[1], HIP_SYMBOL(g_x1h));
    hipGetSymbolAddress((void**)&xl[1], HIP_SYMBOL(g_x1l));
    hipGetSymbolAddress((void**)&zth[0], HIP_SYMBOL(g_zt0h));
    hipGetSymbolAddress((void**)&ztl[0], HIP_SYMBOL(g_zt0l));
    hipGetSymbolAddress((void**)&zth[1], HIP_SYMBOL(g_zt1h));
    hipGetSymbolAddress((void**)&ztl[1], HIP_SYMBOL(g_zt1l));
    hipGetSymbolAddress((void**)&yrh[0], HIP_SYMBOL(g_yr0h));
    hipGetSymbolAddress((void**)&yrl[0], HIP_SYMBOL(g_yr0l));
    hipGetSymbolAddress((void**)&yrh[1], HIP_SYMBOL(g_yr1h));
    hipGetSymbolAddress((void**)&yrl[1], HIP_SYMBOL(g_yr1l));

    const dim3 gSmall(Ff/64, Nn/64);
    const dim3 gXT(Ff/64, Nn/64);
    const dim3 gME(Nn/64, Nn/64);
    const dim3 gGT(Ff/64, Ff/64);
    const dim3 gGram(4, 4, 16);
    const dim3 gGram2(4, 4, 32);
    const dim3 gGT2(4, 4, 2);
    const dim3 gRed(Ff/64, Nn/64);

    // ---- startup ----
    k_split4<<<NNx/4/256, 256, 0, stream>>>((ushort4*)w1h, (ushort4*)w1l, (const float4*)w1p, NNx/4);
    k_splitME2<<<gME, 256, 0, stream>>>(meh, mel, mth, mtl, EAp, w22p);
    k_split4<<<NF/4/256, 256, 0, stream>>>((ushort4*)yrh[0], (ushort4*)yrl[0], (const float4*)feat, NF/4);
    k_splitXT<<<gXT, 256, 0, stream>>>(xh[0], xl[0], feat);
    k_splitXT<<<gXT, 256, 0, stream>>>(zth[0], ztl[0], z0i);
    k_hkeys_clear<<<TSZ/256, 256, 0, stream>>>(hK);
    k_hsetup<<<Ne/256, 256, 0, stream>>>(hK, slot, ei, ej);
    k_zeroi<<<Nn/256, 256, 0, stream>>>(cntI, Nn);
    k_zeroi<<<Nn/256, 256, 0, stream>>>(cntJ, Nn);
    k_count<<<Ne/256, 256, 0, stream>>>(cntI, cntJ, ei, ej);
    k_scan<<<1, 1024, 0, stream>>>(cntI, rpI);
    k_scan<<<1, 1024, 0, stream>>>(cntJ, rpJ);
    k_zeroi<<<Nn/256, 256, 0, stream>>>(fI, Nn);
    k_zeroi<<<Nn/256, 256, 0, stream>>>(fJ, Nn);
    k_fillcsr<<<Ne/256, 256, 0, stream>>>(rpI, rpJ, fI, fJ, lI, lJ, ei, ej);

    const float* yv = feat;  const float* zv = z0i;
    for (int t = 1; t <= 4; ++t){
        int ri = (t-1) & 1, wi = t & 1;
        u16 *xhc = xh[ri], *xlc = xl[ri], *xhn = xh[wi], *xln = xl[wi];
        u16 *zthc = zth[ri], *ztlc = ztl[ri], *zthn = zth[wi], *ztln = ztl[wi];
        u16 *yrhc = yrh[ri], *yrlc = yrl[ri], *yrhn = yrh[wi], *yrln = yrl[wi];
        float* yn = (t & 1) ? yA : yB;
        float* zn = (t & 1) ? zA : zB;
        const float* ccv = (t == 1) ? evp : cc;

        // 1+2. t1 base (t>1 uses G prefetched at previous layer's step 8)
        if (t == 1){
            k_gram_mm<<<gGram, 256, 0, stream>>>(Gp, xhc, xlc, xhc, xlc);
            k_splitGT<<<gGT, 256, 0, stream>>>(gth, gtl, Gp);
            k_zero<<<1, 256, 0, stream>>>(col, Ff);
            k_colsum<<<64, 256, 0, stream>>>(col, yv);
            k_mm<4><<<gSmall, 256, 0, stream>>>(t1, yrhc, yrlc, gth, gtl, col);
        } else {
            k_mm<3><<<gSmall, 256, 0, stream>>>(t1, yrhc, yrlc, g2h, g2l, T1);
        }
        // 3. batched dense GEMMs (KSP=4): b0 = mEA@y, b1 = mEA@z, b2 = mEA^T@y (t>=2)
        {
            int nb = (t == 1) ? 2 : 3;
            dim3 gB(4, Nn/64, nb);
            k_mmB<4><<<gB, 512, 0, stream>>>(pb,
                meh, mel, xhc, xlc,
                meh, mel, zthc, ztlc,
                mth, mtl, xhc, xlc);
        }
        // 4+5. fused: CSR + plane reduce + t1 finish + transpose split + zn
        if (t == 1)
            k_csrRed<0><<<gRed, 256, 0, stream>>>(t1, zn, yv, zv, pb, ccv, P,
                                                  rpI, lI, ej, rpJ, lJ, ei, tth, ttl);
        else
            k_csrRed<1><<<gRed, 256, 0, stream>>>(t1, zn, yv, zv, pb, ccv, P,
                                                  rpI, lI, ej, rpJ, lJ, ei, tth, ttl);
        // 6. z^T split for next layer (post-sparse z)
        if (t < 4)
            k_splitXT<<<gXT, 256, 0, stream>>>(zthn, ztln, zn);
        // 7. yn = feat + 0.5*sigmoid(w1@t1) (KSP=8, 512 blocks = 2/CU)
        {
            dim3 gB(8, Nn/64, 1);
            k_mmB<8><<<gB, 512, 0, stream>>>(pb,
                w1h, w1l, tth, ttl,
                w1h, w1l, tth, ttl,
                w1h, w1l, tth, ttl);
        }
        k_redY<<<gRed, 256, 0, stream>>>(yn, pb, feat, yrhn, yrln, xhn, xln);
        // 8. next-layer EP coefficients, batched Grams, T1 carry (uses OLD y,z)
        if (t < 4){
            k_zero<<<TSZ/256, 256, 0, stream>>>(hV, TSZ);
            k_pacc<<<Ne/4, 256, 0, stream>>>(P, hV, zv, ei, ej, evp, slot);
            k_ep<<<Ne/4, 256, 0, stream>>>(cc, yv, ei, ej, evp, hV, slot);
            k_gram_mm2<<<gGram2, 256, 0, stream>>>(Gp, xhc, xlc, xhn, xln);   // [y^T yn | yn^T yn]
            k_splitGT2<<<gGT2, 256, 0, stream>>>(gth, gtl, g2h, g2l, Gp);
            k_mm<5><<<gSmall, 256, 0, stream>>>(T1, yrhc, yrlc, gth, gtl, nullptr);
        }
        yv = yn; zv = zn;
    }
    k_head<<<Nn, 256, 0, stream>>>(out, yv, zv, w2w, w2b);
}

// Round 15
// 1350.454 us; speedup vs baseline: 1.5820x; 1.5820x over previous
//
#include <hip/hip_runtime.h>

#define Nn 4096
#define Ff 256
#define NCLS 16
#define Ne 65536
#define TSZ 262144
#define NF (Nn*Ff)
#define NNx (Nn*Nn)

typedef unsigned short u16;
typedef unsigned int u32;
typedef __attribute__((ext_vector_type(8))) short short8;
typedef __attribute__((ext_vector_type(4))) float float4v;

__device__ __forceinline__ float bfh(u16 u){ return __uint_as_float(((u32)u)<<16); }
__device__ __forceinline__ u16 f2bf(float f){
    u32 u = __float_as_uint(f);
    return (u16)((u + 0x7FFFu + ((u>>16)&1u)) >> 16);
}
__device__ __forceinline__ void gload16(const u16* g, u16* l){
    __builtin_amdgcn_global_load_lds(
        (const __attribute__((address_space(1))) u32*)(const void*)g,
        (__attribute__((address_space(3))) u32*)(void*)l, 16, 0, 0);
}

// ---------------- device-global workspace ----------------
__device__ float g_yA[NF], g_yB[NF], g_zA[NF], g_zB[NF], g_t1[NF], g_T1[NF];
__device__ float g_Gp[32*Ff*Ff], g_col[Ff], g_P[Ne], g_cc[Ne], g_hV[TSZ];
__device__ float g_pb[(size_t)24*NF];
__device__ u32 g_hK[TSZ], g_slot[Ne];
__device__ int g_cntI[Nn], g_cntJ[Nn], g_rpI[Nn+1], g_rpJ[Nn+1], g_fI[Nn], g_fJ[Nn];
__device__ int g_lI[Ne], g_lJ[Ne];
__device__ __align__(16) u16 g_w1h[NNx], g_w1l[NNx];
__device__ __align__(16) u16 g_meh[NNx], g_mel[NNx];
__device__ __align__(16) u16 g_mth[NNx], g_mtl[NNx];
__device__ __align__(16) u16 g_x0h[NF], g_x0l[NF], g_x1h[NF], g_x1l[NF];     // y^T splits (dbuf)
__device__ __align__(16) u16 g_zt0h[NF], g_zt0l[NF], g_zt1h[NF], g_zt1l[NF]; // z^T splits (dbuf)
__device__ __align__(16) u16 g_yr0h[NF], g_yr0l[NF], g_yr1h[NF], g_yr1l[NF]; // y row splits (dbuf)
__device__ __align__(16) u16 g_tth[NF], g_ttl[NF];                           // t1^T split
__device__ __align__(16) u16 g_gth[Ff*Ff], g_gtl[Ff*Ff];
__device__ __align__(16) u16 g_g2h[Ff*Ff], g_g2l[Ff*Ff];                     // next-layer G prefetch

// ---------------- utility ----------------
__global__ __launch_bounds__(256) void k_zero(float* p, int n){
    int i = blockIdx.x*256 + threadIdx.x;
    if (i < n) p[i] = 0.f;
}
__global__ __launch_bounds__(256) void k_zeroi(int* p, int n){
    int i = blockIdx.x*256 + threadIdx.x;
    if (i < n) p[i] = 0;
}
__global__ __launch_bounds__(256) void k_fillc(float* p, float v, int n){
    int i = blockIdx.x*256 + threadIdx.x;
    if (i < n) p[i] = v;
}
__global__ __launch_bounds__(256) void k_hkeys_clear(u32* K){
    int i = blockIdx.x*256 + threadIdx.x;
    if (i < TSZ) K[i] = 0xFFFFFFFFu;
}
__global__ __launch_bounds__(256) void k_hsetup(u32* K, u32* slot, const int* ei, const int* ej){
    int e = blockIdx.x*256 + threadIdx.x;
    if (e >= Ne) return;
    u32 key = ((u32)ei[e] << 12) | (u32)ej[e];
    u32 h = (key * 2654435761u) & (TSZ-1);
    for (;;){
        u32 old = atomicCAS(&K[h], 0xFFFFFFFFu, key);
        if (old == 0xFFFFFFFFu || old == key){ slot[e] = h; break; }
        h = (h+1) & (TSZ-1);
    }
}

// ---------------- CSR build ----------------
__global__ __launch_bounds__(256) void k_count(int* cntI, int* cntJ, const int* ei, const int* ej){
    int e = blockIdx.x*256 + threadIdx.x;
    if (e < Ne){ atomicAdd(&cntI[ei[e]], 1); atomicAdd(&cntJ[ej[e]], 1); }
}
__global__ __launch_bounds__(1024) void k_scan(const int* cnt, int* rp){
    __shared__ int s[1024];
    int t = threadIdx.x, b = t*4;
    int a0 = cnt[b], a1 = cnt[b+1], a2 = cnt[b+2], a3 = cnt[b+3];
    int sum = a0+a1+a2+a3;
    s[t] = sum; __syncthreads();
    for (int o = 1; o < 1024; o <<= 1){
        int v = (t >= o) ? s[t-o] : 0;
        __syncthreads();
        s[t] += v;
        __syncthreads();
    }
    int excl = s[t] - sum;
    rp[b] = excl; rp[b+1] = excl+a0; rp[b+2] = excl+a0+a1; rp[b+3] = excl+a0+a1+a2;
    if (t == 1023) rp[4096] = s[1023];
}
__global__ __launch_bounds__(256) void k_fillcsr(const int* rpI, const int* rpJ, int* fI, int* fJ,
                                                 int* lI, int* lJ, const int* ei, const int* ej){
    int e = blockIdx.x*256 + threadIdx.x;
    if (e >= Ne) return;
    int i = ei[e], j = ej[e];
    lI[rpI[i] + atomicAdd(&fI[i], 1)] = e;
    lJ[rpJ[j] + atomicAdd(&fJ[j], 1)] = e;
}

// ---------------- split precompute ----------------
__global__ __launch_bounds__(256) void k_split4(ushort4* hi, ushort4* lo, const float4* w, int n4){
    int i = blockIdx.x*256 + threadIdx.x;
    if (i >= n4) return;
    float4 v = w[i];
    ushort4 h, l;
    h.x = f2bf(v.x); l.x = f2bf(v.x - bfh(h.x));
    h.y = f2bf(v.y); l.y = f2bf(v.y - bfh(h.y));
    h.z = f2bf(v.z); l.z = f2bf(v.z - bfh(h.z));
    h.w = f2bf(v.w); l.w = f2bf(v.w - bfh(h.w));
    hi[i] = h; lo[i] = l;
}
// fused mEA (row-major) + mEA^T split — r6 scalar version (HBM-roofline, 0 conflicts)
__global__ __launch_bounds__(256) void k_splitME2(u16* meh, u16* mel, u16* mth, u16* mtl,
                                                  const float* ea, const float* w22){
    __shared__ float T[64][65];
    int r0 = blockIdx.y*64, c0 = blockIdx.x*64;
    int c = threadIdx.x & 63, rr = threadIdx.x >> 6;
    for (int q = 0; q < 16; ++q){
        int r = q*4 + rr;
        size_t idx = (size_t)(r0+r)*Nn + c0 + c;
        float v = 0.5f*ea[idx]*w22[idx];
        T[r][c] = v;
        u16 h = f2bf(v); meh[idx] = h; mel[idx] = f2bf(v - bfh(h));
    }
    __syncthreads();
    for (int q = 0; q < 16; ++q){
        int r = q*4 + rr;
        float v = T[c][r];
        size_t o = (size_t)(c0+r)*Nn + r0 + c;
        u16 h = f2bf(v); mth[o] = h; mtl[o] = f2bf(v - bfh(h));
    }
}
// X [4096][256] f32 -> X^T split [256][4096]
__global__ __launch_bounds__(256) void k_splitXT(u16* hi, u16* lo, const float* X){
    __shared__ float T[64][65];
    int r0 = blockIdx.y*64, c0 = blockIdx.x*64;
    int c = threadIdx.x & 63, rr = threadIdx.x >> 6;
    for (int q = 0; q < 16; ++q){
        int r = q*4 + rr;
        T[r][c] = X[(size_t)(r0+r)*Ff + c0 + c];
    }
    __syncthreads();
    for (int q = 0; q < 16; ++q){
        int r = q*4 + rr;
        float v = T[c][r];
        size_t o = (size_t)(c0+r)*Nn + r0 + c;
        u16 h = f2bf(v); hi[o] = h; lo[o] = f2bf(v - bfh(h));
    }
}
// sum 16 G-planes (base 0) -> G^T split
__global__ __launch_bounds__(256) void k_splitGT(u16* hi, u16* lo, const float* Gp){
    __shared__ float T[64][65];
    int r0 = blockIdx.y*64, c0 = blockIdx.x*64;
    int c = threadIdx.x & 63, rr = threadIdx.x >> 6;
    for (int q = 0; q < 16; ++q){
        int r = q*4 + rr;
        float v = 0.f;
        #pragma unroll
        for (int z = 0; z < 16; ++z) v += Gp[z*(Ff*Ff) + (r0+r)*Ff + c0 + c];
        T[r][c] = v;
    }
    __syncthreads();
    for (int q = 0; q < 16; ++q){
        int r = q*4 + rr;
        float v = T[c][r];
        int o = (c0+r)*Ff + r0 + c;
        u16 h = f2bf(v); hi[o] = h; lo[o] = f2bf(v - bfh(h));
    }
}
// batched: z=0 -> planes 0..15 -> (h0,l0); z=1 -> planes 16..31 -> (h1,l1)
__global__ __launch_bounds__(256) void k_splitGT2(u16* h0, u16* l0, u16* h1, u16* l1,
                                                  const float* Gp){
    __shared__ float T[64][65];
    const int which = blockIdx.z;
    u16* hi = which ? h1 : h0;
    u16* lo = which ? l1 : l0;
    const float* G = Gp + (size_t)which*16*(Ff*Ff);
    int r0 = blockIdx.y*64, c0 = blockIdx.x*64;
    int c = threadIdx.x & 63, rr = threadIdx.x >> 6;
    for (int q = 0; q < 16; ++q){
        int r = q*4 + rr;
        float v = 0.f;
        #pragma unroll
        for (int z = 0; z < 16; ++z) v += G[z*(Ff*Ff) + (r0+r)*Ff + c0 + c];
        T[r][c] = v;
    }
    __syncthreads();
    for (int q = 0; q < 16; ++q){
        int r = q*4 + rr;
        float v = T[c][r];
        int o = (c0+r)*Ff + r0 + c;
        u16 h = f2bf(v); hi[o] = h; lo[o] = f2bf(v - bfh(h));
    }
}

// ---------------- small-GEMM MFMA tile core (verified r5-r12) ----------------
__device__ __forceinline__ void mm_tile(
    const u16* __restrict__ Ahp, const u16* __restrict__ Alp,
    const u16* __restrict__ Bhp, const u16* __restrict__ Blp,
    size_t sA, size_t sB, int i0, int j0, int k0,
    u16* LAh, u16* LAl, u16* LBh, u16* LBl,
    float4v* acc, int lane, int w)
{
    const int g1 = w*64 + lane;
    const int g2 = g1 + 256;
    const int r1 = g1>>3, p1 = g1&7, r2 = g2>>3, p2 = g2&7;
    const size_t a1 = (size_t)(i0+r1)*sA + (size_t)(k0 + ((p1 ^ (r1&7))<<3));
    const size_t a2 = (size_t)(i0+r2)*sA + (size_t)(k0 + ((p2 ^ (r2&7))<<3));
    const size_t b1 = (size_t)(j0+r1)*sB + (size_t)(k0 + ((p1 ^ (r1&7))<<3));
    const size_t b2 = (size_t)(j0+r2)*sB + (size_t)(k0 + ((p2 ^ (r2&7))<<3));
    __syncthreads();
    gload16(Ahp + a1, LAh + g1*8);
    gload16(Ahp + a2, LAh + g2*8);
    gload16(Alp + a1, LAl + g1*8);
    gload16(Alp + a2, LAl + g2*8);
    gload16(Bhp + b1, LBh + g1*8);
    gload16(Bhp + b2, LBh + g2*8);
    gload16(Blp + b1, LBl + g1*8);
    gload16(Blp + b2, LBl + g2*8);
    __syncthreads();
    const int arow = w*16 + (lane&15);
    const int aswz = arow & 7;
    #pragma unroll
    for (int kk = 0; kk < 2; ++kk){
        const int ch = kk*4 + (lane>>4);
        short8 ah = *(const short8*)(LAh + arow*64 + ((ch ^ aswz)<<3));
        short8 al = *(const short8*)(LAl + arow*64 + ((ch ^ aswz)<<3));
        #pragma unroll
        for (int c = 0; c < 4; ++c){
            const int brow = c*16 + (lane&15);
            const int bo = brow*64 + ((ch ^ (brow&7))<<3);
            short8 bh = *(const short8*)(LBh + bo);
            short8 bl = *(const short8*)(LBl + bo);
            acc[c] = __builtin_amdgcn_mfma_f32_16x16x32_bf16(ah, bh, acc[c], 0,0,0);
            acc[c] = __builtin_amdgcn_mfma_f32_16x16x32_bf16(ah, bl, acc[c], 0,0,0);
            acc[c] = __builtin_amdgcn_mfma_f32_16x16x32_bf16(al, bh, acc[c], 0,0,0);
        }
    }
}

// small GEMM (K=256): V3: out=aux-acc  V4: out=aux[col]-acc  V5: out=acc
template<int V>
__global__ __launch_bounds__(256) void k_mm(float* __restrict__ out,
        const u16* __restrict__ Ahp, const u16* __restrict__ Alp,
        const u16* __restrict__ Bhp, const u16* __restrict__ Blp,
        const float* __restrict__ aux1){
    __shared__ u16 LAh[4096], LAl[4096], LBh[4096], LBl[4096];
    const int tid = threadIdx.x, lane = tid & 63, w = tid >> 6;
    const int j0 = blockIdx.x*64, i0 = blockIdx.y*64;
    float4v acc[4];
    #pragma unroll
    for (int c = 0; c < 4; ++c) acc[c] = (float4v){0.f,0.f,0.f,0.f};
    for (int kt = 0; kt < 4; ++kt)
        mm_tile(Ahp, Alp, Bhp, Blp, (size_t)Ff, (size_t)Ff, i0, j0, kt*64, LAh, LAl, LBh, LBl, acc, lane, w);
    #pragma unroll
    for (int c = 0; c < 4; ++c)
        #pragma unroll
        for (int r = 0; r < 4; ++r){
            int grow = i0 + w*16 + (lane>>4)*4 + r;
            int gcol = j0 + c*16 + (lane&15);
            size_t idx = (size_t)grow*Ff + gcol;
            float v = acc[c][r];
            if constexpr (V == 3) out[idx] = aux1[idx] - v;
            if constexpr (V == 4) out[idx] = aux1[gcol] - v;
            if constexpr (V == 5) out[idx] = v;
        }
}

// Gram GEMM (single): Gp[z] = partial over K-chunk
__global__ __launch_bounds__(256) void k_gram_mm(float* __restrict__ Gp,
        const u16* __restrict__ Ahp, const u16* __restrict__ Alp,
        const u16* __restrict__ Bhp, const u16* __restrict__ Blp){
    __shared__ u16 LAh[4096], LAl[4096], LBh[4096], LBl[4096];
    const int tid = threadIdx.x, lane = tid & 63, w = tid >> 6;
    const int j0 = blockIdx.x*64, i0 = blockIdx.y*64, kb = blockIdx.z*256;
    float4v acc[4];
    #pragma unroll
    for (int c = 0; c < 4; ++c) acc[c] = (float4v){0.f,0.f,0.f,0.f};
    for (int kt = 0; kt < 4; ++kt)
        mm_tile(Ahp, Alp, Bhp, Blp, (size_t)Nn, (size_t)Nn, i0, j0, kb + kt*64, LAh, LAl, LBh, LBl, acc, lane, w);
    float* op = Gp + (size_t)blockIdx.z*(Ff*Ff);
    #pragma unroll
    for (int c = 0; c < 4; ++c)
        #pragma unroll
        for (int r = 0; r < 4; ++r){
            int grow = i0 + w*16 + (lane>>4)*4 + r;
            int gcol = j0 + c*16 + (lane&15);
            op[grow*Ff + gcol] = acc[c][r];
        }
}

// Batched Gram: z=0..15 -> (A,B) pair [y_old^T y_new]; z=16..31 -> (B,B) [y_new^T y_new]
__global__ __launch_bounds__(256) void k_gram_mm2(float* __restrict__ Gp,
        const u16* __restrict__ Ahp, const u16* __restrict__ Alp,
        const u16* __restrict__ Bhp, const u16* __restrict__ Blp){
    __shared__ u16 LAh[4096], LAl[4096], LBh[4096], LBl[4096];
    const int tid = threadIdx.x, lane = tid & 63, w = tid >> 6;
    const int j0 = blockIdx.x*64, i0 = blockIdx.y*64;
    const int pz = blockIdx.z;
    const int kb = (pz & 15)*256, which = pz >> 4;
    const u16* pAh = which ? Bhp : Ahp;
    const u16* pAl = which ? Blp : Alp;
    float4v acc[4];
    #pragma unroll
    for (int c = 0; c < 4; ++c) acc[c] = (float4v){0.f,0.f,0.f,0.f};
    for (int kt = 0; kt < 4; ++kt)
        mm_tile(pAh, pAl, Bhp, Blp, (size_t)Nn, (size_t)Nn, i0, j0, kb + kt*64, LAh, LAl, LBh, LBl, acc, lane, w);
    float* op = Gp + (size_t)pz*(Ff*Ff);
    #pragma unroll
    for (int c = 0; c < 4; ++c)
        #pragma unroll
        for (int r = 0; r < 4; ++r){
            int grow = i0 + w*16 + (lane>>4)*4 + r;
            int gcol = j0 + c*16 + (lane&15);
            op[grow*Ff + gcol] = acc[c][r];
        }
}

// ---------------- big GEMM (r12-verified core, templated K-split) ----------------
// BM=64, BN=256, BK=64, 512 thr, 80 KB LDS -> 2 blocks/CU.
// grid: (KSP, 64, nb): x = K-plane, y = i-block, z = batch. 64/KSP kt per block.
template<int KSP>
__global__ __launch_bounds__(512) void k_mmB(float* __restrict__ pb,
        const u16* __restrict__ A0h, const u16* __restrict__ A0l,
        const u16* __restrict__ B0h, const u16* __restrict__ B0l,
        const u16* __restrict__ A1h, const u16* __restrict__ A1l,
        const u16* __restrict__ B1h, const u16* __restrict__ B1l,
        const u16* __restrict__ A2h, const u16* __restrict__ A2l,
        const u16* __restrict__ B2h, const u16* __restrict__ B2l){
    __shared__ u16 LAh[4096], LAl[4096], LBh[16384], LBl[16384];
    const int tid = threadIdx.x, lane = tid & 63, w = tid >> 6;
    const int z = blockIdx.x, i0 = blockIdx.y*64, bat = blockIdx.z;
    const u16 *Ah, *Al, *Bh, *Bl;
    if (bat == 0){ Ah = A0h; Al = A0l; Bh = B0h; Bl = B0l; }
    else if (bat == 1){ Ah = A1h; Al = A1l; Bh = B1h; Bl = B1l; }
    else { Ah = A2h; Al = A2l; Bh = B2h; Bl = B2l; }
    const int wr = w >> 2, wc = w & 3;
    float4v acc[2][4];
    #pragma unroll
    for (int m = 0; m < 2; ++m)
        #pragma unroll
        for (int n = 0; n < 4; ++n) acc[m][n] = (float4v){0.f,0.f,0.f,0.f};

    const int ra = tid >> 3, pa = tid & 7;
    const size_t aoff = (size_t)(i0+ra)*Nn + (size_t)((pa ^ (ra&7))<<3);
    constexpr int NKT = 64 / KSP;

    for (int kt = 0; kt < NKT; ++kt){
        const int k0 = z*(NKT*64) + kt*64;
        __syncthreads();
        gload16(Ah + aoff + k0, LAh + tid*8);
        gload16(Al + aoff + k0, LAl + tid*8);
        #pragma unroll
        for (int it = 0; it < 4; ++it){
            int g = it*512 + tid;
            int r = g >> 3, p = g & 7;
            size_t b = (size_t)r*Nn + (size_t)(k0 + ((p ^ (r&7))<<3));
            gload16(Bh + b, LBh + g*8);
            gload16(Bl + b, LBl + g*8);
        }
        __syncthreads();
        #pragma unroll
        for (int kk = 0; kk < 2; ++kk){
            const int ch = kk*4 + (lane>>4);
            short8 ah0, ah1, al0, al1;
            {
                const int arow = wr*32 + (lane&15);
                const int ao = arow*64 + ((ch ^ (arow&7))<<3);
                ah0 = *(const short8*)(LAh + ao);
                al0 = *(const short8*)(LAl + ao);
            }
            {
                const int arow = wr*32 + 16 + (lane&15);
                const int ao = arow*64 + ((ch ^ (arow&7))<<3);
                ah1 = *(const short8*)(LAh + ao);
                al1 = *(const short8*)(LAl + ao);
            }
            #pragma unroll
            for (int n = 0; n < 4; ++n){
                const int bcol = wc*64 + n*16 + (lane&15);
                const int bo = bcol*64 + ((ch ^ (bcol&7))<<3);
                short8 bh = *(const short8*)(LBh + bo);
                short8 bl = *(const short8*)(LBl + bo);
                acc[0][n] = __builtin_amdgcn_mfma_f32_16x16x32_bf16(ah0, bh, acc[0][n], 0,0,0);
                acc[0][n] = __builtin_amdgcn_mfma_f32_16x16x32_bf16(ah0, bl, acc[0][n], 0,0,0);
                acc[0][n] = __builtin_amdgcn_mfma_f32_16x16x32_bf16(al0, bh, acc[0][n], 0,0,0);
                acc[1][n] = __builtin_amdgcn_mfma_f32_16x16x32_bf16(ah1, bh, acc[1][n], 0,0,0);
                acc[1][n] = __builtin_amdgcn_mfma_f32_16x16x32_bf16(ah1, bl, acc[1][n], 0,0,0);
                acc[1][n] = __builtin_amdgcn_mfma_f32_16x16x32_bf16(al1, bh, acc[1][n], 0,0,0);
            }
        }
    }
    float* op = pb + ((size_t)bat*KSP + z)*NF;
    #pragma unroll
    for (int m = 0; m < 2; ++m)
        #pragma unroll
        for (int n = 0; n < 4; ++n)
            #pragma unroll
            for (int r = 0; r < 4; ++r){
                int row = i0 + wr*32 + m*16 + (lane>>4)*4 + r;
                int col = wc*64 + n*16 + (lane&15);
                op[(size_t)row*Ff + col] = acc[m][n][r];
            }
}

// t1 final reduce (3-batch uses KSP=4): t1 += sum(pb[0..3]) - (HASM? sum(pb[8..11]) : 0);
// transpose-split to th/tl
template<int HASM, int DOSPLIT>
__global__ __launch_bounds__(256) void k_redT1(float* __restrict__ t1, const float* __restrict__ pb,
        u16* __restrict__ th, u16* __restrict__ tl){
    __shared__ float T[64][65];
    const int c0 = blockIdx.x*64, r0 = blockIdx.y*64;
    const int c = threadIdx.x & 63, rr = threadIdx.x >> 6;
    for (int q = 0; q < 16; ++q){
        int row = q*4 + rr;
        size_t idx = (size_t)(r0+row)*Ff + c0 + c;
        float s = 0.f;
        #pragma unroll
        for (int p = 0; p < 4; ++p) s += pb[(size_t)p*NF + idx];
        if constexpr (HASM){
            #pragma unroll
            for (int p = 0; p < 4; ++p) s -= pb[((size_t)8 + p)*NF + idx];
        }
        float val = t1[idx] + s;
        t1[idx] = val;
        if constexpr (DOSPLIT) T[row][c] = val;
    }
    if constexpr (DOSPLIT){
        __syncthreads();
        for (int q = 0; q < 16; ++q){
            int r = q*4 + rr;
            float v = T[c][r];
            size_t o = (size_t)(c0+r)*Nn + r0 + c;
            u16 h = f2bf(v); th[o] = h; tl[o] = f2bf(v - bfh(h));
        }
    }
}

// yn epilogue (w1 uses KSP=8): yn = feat + 0.5*sigmoid(sum(pb[0..7])); row + transpose splits
__global__ __launch_bounds__(256) void k_redY(float* __restrict__ yn, const float* __restrict__ pb,
        const float* __restrict__ feat, u16* __restrict__ rh, u16* __restrict__ rl,
        u16* __restrict__ th, u16* __restrict__ tl){
    __shared__ float T[64][65];
    const int c0 = blockIdx.x*64, r0 = blockIdx.y*64;
    const int c = threadIdx.x & 63, rr = threadIdx.x >> 6;
    for (int q = 0; q < 16; ++q){
        int row = q*4 + rr;
        size_t idx = (size_t)(r0+row)*Ff + c0 + c;
        float s = 0.f;
        #pragma unroll
        for (int p = 0; p < 8; ++p) s += pb[(size_t)p*NF + idx];
        float val = feat[idx] + 0.5f*(1.f/(1.f+expf(-s)));
        yn[idx] = val;
        u16 h = f2bf(val); rh[idx] = h; rl[idx] = f2bf(val - bfh(h));
        T[row][c] = val;
    }
    __syncthreads();
    for (int q = 0; q < 16; ++q){
        int r = q*4 + rr;
        float v = T[c][r];
        size_t o = (size_t)(c0+r)*Nn + r0 + c;
        u16 h = f2bf(v); th[o] = h; tl[o] = f2bf(v - bfh(h));
    }
}

// ---------------- fused CSR sparse + z dense (pb1 = 4 planes) ----------------
__global__ __launch_bounds__(256) void k_csrTZ(float* __restrict__ t1, float* __restrict__ zn,
        const float* __restrict__ y, const float* __restrict__ z, const float* __restrict__ pb1,
        const float* __restrict__ cc, const float* __restrict__ P,
        const int* __restrict__ rpI, const int* __restrict__ lI, const int* __restrict__ ej,
        const int* __restrict__ rpJ, const int* __restrict__ lJ, const int* __restrict__ ei,
        int useM){
    const int r = blockIdx.x, f = threadIdx.x;
    float at = 0.f, az = 0.f;
    const int b0 = rpI[r], b1 = rpI[r+1];
    for (int p = b0; p < b1; ++p){
        int e = lI[p];
        float ce = cc[e];
        int j = ej[e];
        at += ce * y[(size_t)j*Ff + f];
        az += ce * z[(size_t)j*Ff + f];
    }
    if (useM){
        const int c0 = rpJ[r], c1 = rpJ[r+1];
        for (int p = c0; p < c1; ++p){
            int e = lJ[p];
            at -= 0.5f * P[e] * y[(size_t)ei[e]*Ff + f];
        }
    }
    size_t idx = (size_t)r*Ff + f;
    float dz = 0.f;
    #pragma unroll
    for (int p = 0; p < 4; ++p) dz += pb1[(size_t)p*NF + idx];
    t1[idx] += at;
    zn[idx] = z[idx] - dz - az;
}

__global__ __launch_bounds__(256) void k_colsum(float* col, const float* __restrict__ y){
    int j = threadIdx.x;
    int r0 = blockIdx.x*64;
    float s = 0.f;
    for (int i = 0; i < 64; ++i) s += y[(size_t)(r0+i)*Ff + j];
    atomicAdd(&col[j], s);
}

// ---------------- per-edge kernels ----------------
__global__ __launch_bounds__(256) void k_pacc(float* __restrict__ P, float* __restrict__ hV,
        const float* __restrict__ z, const int* __restrict__ ei, const int* __restrict__ ej,
        const float* __restrict__ ev, const u32* __restrict__ slot){
    int e = blockIdx.x*4 + (threadIdx.x >> 6);
    int lane = threadIdx.x & 63;
    int i = ei[e], j = ej[e];
    float s = 0.f;
    #pragma unroll
    for (int q = 0; q < 4; ++q){
        int f = lane + q*64;
        float d = z[(size_t)i*Ff + f] - z[(size_t)j*Ff + f];
        s += d*d;
    }
    #pragma unroll
    for (int o = 32; o; o >>= 1) s += __shfl_xor(s, o);
    if (lane == 0){
        float v = sqrtf(s) * ev[e];
        P[e] = v;
        atomicAdd(&hV[slot[e]], v);
    }
}
__global__ __launch_bounds__(256) void k_ep(float* __restrict__ c, const float* __restrict__ y,
        const int* __restrict__ ei, const int* __restrict__ ej, const float* __restrict__ ev,
        const float* __restrict__ V, const u32* __restrict__ slot){
    int e = blockIdx.x*4 + (threadIdx.x >> 6);
    int lane = threadIdx.x & 63;
    int i = ei[e], j = ej[e];
    float s = 0.f;
    #pragma unroll
    for (int q = 0; q < 4; ++q){
        int f = lane + q*64;
        s += y[(size_t)i*Ff + f] * y[(size_t)j*Ff + f];
    }
    #pragma unroll
    for (int o = 32; o; o >>= 1) s += __shfl_xor(s, o);
    if (lane == 0) c[e] = ev[e] * (s - 0.5f * V[slot[e]]);
}

// ---------------- head ----------------
__global__ __launch_bounds__(256) void k_head(float* __restrict__ out, const float* __restrict__ y,
                                              const float* __restrict__ z, const float* __restrict__ w2w,
                                              const float* __restrict__ w2b){
    const int node = blockIdx.x, t = threadIdx.x;
    float yv = y[(size_t)node*Ff + t], zv = z[(size_t)node*Ff + t];
    float yc = fminf(fmaxf(yv, -1e37f), 1e37f);
    float zc = fminf(fmaxf(zv, -1e37f), 1e37f);
    __shared__ float sy[256], sz[256];
    sy[t] = fabsf(yc); sz[t] = fabsf(zc);
    __syncthreads();
    for (int s = 128; s; s >>= 1){ if (t < s){ sy[t]=fmaxf(sy[t],sy[t+s]); sz[t]=fmaxf(sz[t],sz[t+s]); } __syncthreads(); }
    float my_ = fmaxf(sy[0], 1e-30f), mz_ = fmaxf(sz[0], 1e-30f);
    __syncthreads();
    float ysc = yc/my_, zsc = zc/mz_;
    sy[t] = ysc*ysc; sz[t] = zsc*zsc;
    __syncthreads();
    for (int s = 128; s; s >>= 1){ if (t < s){ sy[t]+=sy[t+s]; sz[t]+=sz[t+s]; } __syncthreads(); }
    float ny = fmaxf(my_*sqrtf(sy[0]), 1e-12f);
    float nz = fmaxf(mz_*sqrtf(sz[0]), 1e-12f);
    float ynv = yc/ny, znv = zc/nz;
    float acc[NCLS];
    #pragma unroll
    for (int cc = 0; cc < NCLS; ++cc)
        acc[cc] = znv*w2w[t*NCLS+cc] + ynv*w2w[(Ff+t)*NCLS+cc];
    __shared__ float red[NCLS][257];
    #pragma unroll
    for (int cc = 0; cc < NCLS; ++cc) red[cc][t] = acc[cc];
    __syncthreads();
    for (int s = 128; s; s >>= 1){
        if (t < s){
            #pragma unroll
            for (int cc = 0; cc < NCLS; ++cc) red[cc][t] += red[cc][t+s];
        }
        __syncthreads();
    }
    __shared__ float lg[NCLS];
    __shared__ float ml[2];
    if (t < NCLS) lg[t] = red[t][0] + w2b[t];
    __syncthreads();
    if (t == 0){
        float m = -1e30f;
        for (int cc = 0; cc < NCLS; ++cc) m = fmaxf(m, lg[cc]);
        float se = 0.f;
        for (int cc = 0; cc < NCLS; ++cc) se += expf(lg[cc]-m);
        ml[0] = m; ml[1] = logf(se);
    }
    __syncthreads();
    if (t < NCLS) out[(size_t)node*NCLS + t] = lg[t] - ml[0] - ml[1];
}

extern "C" void kernel_launch(void* const* d_in, const int* in_sizes, int n_in,
                              void* d_out, int out_size, void* d_ws, size_t ws_size,
                              hipStream_t stream){
    const float* feat = (const float*)d_in[0];
    const float* z0i  = (const float*)d_in[1];
    const float* w1p  = (const float*)d_in[2];
    const float* EAp  = (const float*)d_in[3];
    const float* w2w  = (const float*)d_in[4];
    const float* w2b  = (const float*)d_in[5];
    const float* w22p = (const float*)d_in[7];
    const float* evp  = (const float*)d_in[8];
    const int* ei   = (const int*)d_in[9];
    const int* ej   = (const int*)d_in[10];
    float* out = (float*)d_out;

    int ok = (n_in == 11) && (out_size == Nn*NCLS)
           && in_sizes[0]==NF && in_sizes[1]==NF && in_sizes[2]==NNx && in_sizes[3]==NNx
           && in_sizes[4]==2*Ff*NCLS && in_sizes[5]==NCLS && in_sizes[6]==NNx && in_sizes[7]==NNx
           && in_sizes[8]==Ne && in_sizes[9]==Ne && in_sizes[10]==Ne;
    if (!ok){
        k_fillc<<<(out_size+255)/256, 256, 0, stream>>>(out, -100.0f, out_size);
        return;
    }

    float *yA,*yB,*zA,*zB,*t1,*T1,*Gp,*col,*P,*cc,*hV,*pb; u32 *hK,*slot;
    int *cntI,*cntJ,*rpI,*rpJ,*fI,*fJ,*lI,*lJ;
    u16 *w1h,*w1l,*meh,*mel,*mth,*mtl,*gth,*gtl,*g2h,*g2l,*tth,*ttl;
    u16 *xh[2],*xl[2],*zth[2],*ztl[2],*yrh[2],*yrl[2];
    hipGetSymbolAddress((void**)&yA,  HIP_SYMBOL(g_yA));
    hipGetSymbolAddress((void**)&yB,  HIP_SYMBOL(g_yB));
    hipGetSymbolAddress((void**)&zA,  HIP_SYMBOL(g_zA));
    hipGetSymbolAddress((void**)&zB,  HIP_SYMBOL(g_zB));
    hipGetSymbolAddress((void**)&t1,  HIP_SYMBOL(g_t1));
    hipGetSymbolAddress((void**)&T1,  HIP_SYMBOL(g_T1));
    hipGetSymbolAddress((void**)&Gp,  HIP_SYMBOL(g_Gp));
    hipGetSymbolAddress((void**)&col, HIP_SYMBOL(g_col));
    hipGetSymbolAddress((void**)&P,   HIP_SYMBOL(g_P));
    hipGetSymbolAddress((void**)&cc,  HIP_SYMBOL(g_cc));
    hipGetSymbolAddress((void**)&hV,  HIP_SYMBOL(g_hV));
    hipGetSymbolAddress((void**)&pb,  HIP_SYMBOL(g_pb));
    hipGetSymbolAddress((void**)&hK,  HIP_SYMBOL(g_hK));
    hipGetSymbolAddress((void**)&slot,HIP_SYMBOL(g_slot));
    hipGetSymbolAddress((void**)&cntI,HIP_SYMBOL(g_cntI));
    hipGetSymbolAddress((void**)&cntJ,HIP_SYMBOL(g_cntJ));
    hipGetSymbolAddress((void**)&rpI, HIP_SYMBOL(g_rpI));
    hipGetSymbolAddress((void**)&rpJ, HIP_SYMBOL(g_rpJ));
    hipGetSymbolAddress((void**)&fI,  HIP_SYMBOL(g_fI));
    hipGetSymbolAddress((void**)&fJ,  HIP_SYMBOL(g_fJ));
    hipGetSymbolAddress((void**)&lI,  HIP_SYMBOL(g_lI));
    hipGetSymbolAddress((void**)&lJ,  HIP_SYMBOL(g_lJ));
    hipGetSymbolAddress((void**)&w1h, HIP_SYMBOL(g_w1h));
    hipGetSymbolAddress((void**)&w1l, HIP_SYMBOL(g_w1l));
    hipGetSymbolAddress((void**)&meh, HIP_SYMBOL(g_meh));
    hipGetSymbolAddress((void**)&mel, HIP_SYMBOL(g_mel));
    hipGetSymbolAddress((void**)&mth, HIP_SYMBOL(g_mth));
    hipGetSymbolAddress((void**)&mtl, HIP_SYMBOL(g_mtl));
    hipGetSymbolAddress((void**)&gth, HIP_SYMBOL(g_gth));
    hipGetSymbolAddress((void**)&gtl, HIP_SYMBOL(g_gtl));
    hipGetSymbolAddress((void**)&g2h, HIP_SYMBOL(g_g2h));
    hipGetSymbolAddress((void**)&g2l, HIP_SYMBOL(g_g2l));
    hipGetSymbolAddress((void**)&tth, HIP_SYMBOL(g_tth));
    hipGetSymbolAddress((void**)&ttl, HIP_SYMBOL(g_ttl));
    hipGetSymbolAddress((void**)&xh[0], HIP_SYMBOL(g_x0h));
    hipGetSymbolAddress((void**)&xl[0], HIP_SYMBOL(g_x0l));
    hipGetSymbolAddress((void**)&xh[1], HIP_SYMBOL(g_x1h));
    hipGetSymbolAddress((void**)&xl[1], HIP_SYMBOL(g_x1l));
    hipGetSymbolAddress((void**)&zth[0], HIP_SYMBOL(g_zt0h));
    hipGetSymbolAddress((void**)&ztl[0], HIP_SYMBOL(g_zt0l));
    hipGetSymbolAddress((void**)&zth[1], HIP_SYMBOL(g_zt1h));
    hipGetSymbolAddress((void**)&ztl[1], HIP_SYMBOL(g_zt1l));
    hipGetSymbolAddress((void**)&yrh[0], HIP_SYMBOL(g_yr0h));
    hipGetSymbolAddress((void**)&yrl[0], HIP_SYMBOL(g_yr0l));
    hipGetSymbolAddress((void**)&yrh[1], HIP_SYMBOL(g_yr1h));
    hipGetSymbolAddress((void**)&yrl[1], HIP_SYMBOL(g_yr1l));

    const dim3 gSmall(Ff/64, Nn/64);
    const dim3 gXT(Ff/64, Nn/64);
    const dim3 gME(Nn/64, Nn/64);
    const dim3 gGT(Ff/64, Ff/64);
    const dim3 gGram(4, 4, 16);
    const dim3 gGram2(4, 4, 32);
    const dim3 gGT2(4, 4, 2);
    const dim3 gRed(Ff/64, Nn/64);

    // ---- startup ----
    k_split4<<<NNx/4/256, 256, 0, stream>>>((ushort4*)w1h, (ushort4*)w1l, (const float4*)w1p, NNx/4);
    k_splitME2<<<gME, 256, 0, stream>>>(meh, mel, mth, mtl, EAp, w22p);
    k_split4<<<NF/4/256, 256, 0, stream>>>((ushort4*)yrh[0], (ushort4*)yrl[0], (const float4*)feat, NF/4);
    k_splitXT<<<gXT, 256, 0, stream>>>(xh[0], xl[0], feat);
    k_splitXT<<<gXT, 256, 0, stream>>>(zth[0], ztl[0], z0i);
    k_hkeys_clear<<<TSZ/256, 256, 0, stream>>>(hK);
    k_hsetup<<<Ne/256, 256, 0, stream>>>(hK, slot, ei, ej);
    k_zeroi<<<Nn/256, 256, 0, stream>>>(cntI, Nn);
    k_zeroi<<<Nn/256, 256, 0, stream>>>(cntJ, Nn);
    k_count<<<Ne/256, 256, 0, stream>>>(cntI, cntJ, ei, ej);
    k_scan<<<1, 1024, 0, stream>>>(cntI, rpI);
    k_scan<<<1, 1024, 0, stream>>>(cntJ, rpJ);
    k_zeroi<<<Nn/256, 256, 0, stream>>>(fI, Nn);
    k_zeroi<<<Nn/256, 256, 0, stream>>>(fJ, Nn);
    k_fillcsr<<<Ne/256, 256, 0, stream>>>(rpI, rpJ, fI, fJ, lI, lJ, ei, ej);

    const float* yv = feat;  const float* zv = z0i;
    for (int t = 1; t <= 4; ++t){
        int ri = (t-1) & 1, wi = t & 1;
        u16 *xhc = xh[ri], *xlc = xl[ri], *xhn = xh[wi], *xln = xl[wi];
        u16 *zthc = zth[ri], *ztlc = ztl[ri], *zthn = zth[wi], *ztln = ztl[wi];
        u16 *yrhc = yrh[ri], *yrlc = yrl[ri], *yrhn = yrh[wi], *yrln = yrl[wi];
        float* yn = (t & 1) ? yA : yB;
        float* zn = (t & 1) ? zA : zB;
        const float* ccv = (t == 1) ? evp : cc;

        // 1+2. t1 base (t>1 uses G prefetched at previous layer's step 8)
        if (t == 1){
            k_gram_mm<<<gGram, 256, 0, stream>>>(Gp, xhc, xlc, xhc, xlc);
            k_splitGT<<<gGT, 256, 0, stream>>>(gth, gtl, Gp);
            k_zero<<<1, 256, 0, stream>>>(col, Ff);
            k_colsum<<<64, 256, 0, stream>>>(col, yv);
            k_mm<4><<<gSmall, 256, 0, stream>>>(t1, yrhc, yrlc, gth, gtl, col);
        } else {
            k_mm<3><<<gSmall, 256, 0, stream>>>(t1, yrhc, yrlc, g2h, g2l, T1);
        }
        // 3. batched dense GEMMs (KSP=4): b0 = mEA@y, b1 = mEA@z, b2 = mEA^T@y (t>=2)
        {
            int nb = (t == 1) ? 2 : 3;
            dim3 gB(4, Nn/64, nb);
            k_mmB<4><<<gB, 512, 0, stream>>>(pb,
                meh, mel, xhc, xlc,
                meh, mel, zthc, ztlc,
                mth, mtl, xhc, xlc);
        }
        // 4. fused sparse + z dense: t1 += sparse_T ; zn = z - sum(pb[4..7]) - sparse_Z
        k_csrTZ<<<Nn, 256, 0, stream>>>(t1, zn, yv, zv, pb + (size_t)4*NF, ccv, P,
                                        rpI, lI, ej, rpJ, lJ, ei, (t >= 2) ? 1 : 0);
        // 5. t1 final dense adds + transpose split
        if (t == 1) k_redT1<0,1><<<gRed, 256, 0, stream>>>(t1, pb, tth, ttl);
        else        k_redT1<1,1><<<gRed, 256, 0, stream>>>(t1, pb, tth, ttl);
        // 6. z^T split for next layer (post-sparse z)
        if (t < 4)
            k_splitXT<<<gXT, 256, 0, stream>>>(zthn, ztln, zn);
        // 7. yn = feat + 0.5*sigmoid(w1@t1) (KSP=8, 512 blocks = 2/CU)
        {
            dim3 gB(8, Nn/64, 1);
            k_mmB<8><<<gB, 512, 0, stream>>>(pb,
                w1h, w1l, tth, ttl,
                w1h, w1l, tth, ttl,
                w1h, w1l, tth, ttl);
        }
        k_redY<<<gRed, 256, 0, stream>>>(yn, pb, feat, yrhn, yrln, xhn, xln);
        // 8. next-layer EP coefficients, batched Grams, T1 carry (uses OLD y,z)
        if (t < 4){
            k_zero<<<TSZ/256, 256, 0, stream>>>(hV, TSZ);
            k_pacc<<<Ne/4, 256, 0, stream>>>(P, hV, zv, ei, ej, evp, slot);
            k_ep<<<Ne/4, 256, 0, stream>>>(cc, yv, ei, ej, evp, hV, slot);
            k_gram_mm2<<<gGram2, 256, 0, stream>>>(Gp, xhc, xlc, xhn, xln);   // [y^T yn | yn^T yn]
            k_splitGT2<<<gGT2, 256, 0, stream>>>(gth, gtl, g2h, g2l, Gp);
            k_mm<5><<<gSmall, 256, 0, stream>>>(T1, yrhc, yrlc, gth, gtl, nullptr);
        }
        yv = yn; zv = zn;
    }
    k_head<<<Nn, 256, 0, stream>>>(out, yv, zv, w2w, w2b);
}

// Round 16
// 1310.092 us; speedup vs baseline: 1.6307x; 1.0308x over previous
//
#include <hip/hip_runtime.h>

#define Nn 4096
#define Ff 256
#define NCLS 16
#define Ne 65536
#define TSZ 262144
#define NF (Nn*Ff)
#define NNx (Nn*Nn)

typedef unsigned short u16;
typedef unsigned int u32;
typedef __attribute__((ext_vector_type(8))) short short8;
typedef __attribute__((ext_vector_type(4))) float float4v;

__device__ __forceinline__ float bfh(u16 u){ return __uint_as_float(((u32)u)<<16); }
__device__ __forceinline__ u16 f2bf(float f){
    u32 u = __float_as_uint(f);
    return (u16)((u + 0x7FFFu + ((u>>16)&1u)) >> 16);
}
__device__ __forceinline__ void gload16(const u16* g, u16* l){
    __builtin_amdgcn_global_load_lds(
        (const __attribute__((address_space(1))) u32*)(const void*)g,
        (__attribute__((address_space(3))) u32*)(void*)l, 16, 0, 0);
}

// ---------------- device-global workspace ----------------
__device__ float g_yA[NF], g_yB[NF], g_zA[NF], g_zB[NF], g_t1[NF], g_T1[NF];
__device__ float g_Gp[32*Ff*Ff], g_col[Ff], g_P[Ne], g_cc[Ne], g_hV[TSZ];
__device__ float g_pb[(size_t)24*NF];
__device__ u32 g_hK[TSZ], g_slot[Ne];
__device__ int g_cntI[Nn], g_cntJ[Nn], g_rpI[Nn+1], g_rpJ[Nn+1], g_fI[Nn], g_fJ[Nn];
__device__ int g_lI[Ne], g_lJ[Ne];
__device__ __align__(16) u16 g_w1h[NNx], g_w1l[NNx];
__device__ __align__(16) u16 g_meh[NNx], g_mel[NNx];
__device__ __align__(16) u16 g_mth[NNx], g_mtl[NNx];
__device__ __align__(16) u16 g_x0h[NF], g_x0l[NF], g_x1h[NF], g_x1l[NF];     // y^T splits (dbuf)
__device__ __align__(16) u16 g_zt0h[NF], g_zt0l[NF], g_zt1h[NF], g_zt1l[NF]; // z^T splits (dbuf)
__device__ __align__(16) u16 g_yr0h[NF], g_yr0l[NF], g_yr1h[NF], g_yr1l[NF]; // y row splits (dbuf)
__device__ __align__(16) u16 g_tth[NF], g_ttl[NF];                           // t1^T split
__device__ __align__(16) u16 g_gth[Ff*Ff], g_gtl[Ff*Ff];
__device__ __align__(16) u16 g_g2h[Ff*Ff], g_g2l[Ff*Ff];                     // next-layer G prefetch

// ---------------- utility ----------------
__global__ __launch_bounds__(256) void k_zero(float* p, int n){
    int i = blockIdx.x*256 + threadIdx.x;
    if (i < n) p[i] = 0.f;
}
__global__ __launch_bounds__(256) void k_zeroi(int* p, int n){
    int i = blockIdx.x*256 + threadIdx.x;
    if (i < n) p[i] = 0;
}
__global__ __launch_bounds__(256) void k_fillc(float* p, float v, int n){
    int i = blockIdx.x*256 + threadIdx.x;
    if (i < n) p[i] = v;
}
__global__ __launch_bounds__(256) void k_hkeys_clear(u32* K){
    int i = blockIdx.x*256 + threadIdx.x;
    if (i < TSZ) K[i] = 0xFFFFFFFFu;
}
__global__ __launch_bounds__(256) void k_hsetup(u32* K, u32* slot, const int* ei, const int* ej){
    int e = blockIdx.x*256 + threadIdx.x;
    if (e >= Ne) return;
    u32 key = ((u32)ei[e] << 12) | (u32)ej[e];
    u32 h = (key * 2654435761u) & (TSZ-1);
    for (;;){
        u32 old = atomicCAS(&K[h], 0xFFFFFFFFu, key);
        if (old == 0xFFFFFFFFu || old == key){ slot[e] = h; break; }
        h = (h+1) & (TSZ-1);
    }
}

// ---------------- CSR build ----------------
__global__ __launch_bounds__(256) void k_count(int* cntI, int* cntJ, const int* ei, const int* ej){
    int e = blockIdx.x*256 + threadIdx.x;
    if (e < Ne){ atomicAdd(&cntI[ei[e]], 1); atomicAdd(&cntJ[ej[e]], 1); }
}
__global__ __launch_bounds__(1024) void k_scan(const int* cnt, int* rp){
    __shared__ int s[1024];
    int t = threadIdx.x, b = t*4;
    int a0 = cnt[b], a1 = cnt[b+1], a2 = cnt[b+2], a3 = cnt[b+3];
    int sum = a0+a1+a2+a3;
    s[t] = sum; __syncthreads();
    for (int o = 1; o < 1024; o <<= 1){
        int v = (t >= o) ? s[t-o] : 0;
        __syncthreads();
        s[t] += v;
        __syncthreads();
    }
    int excl = s[t] - sum;
    rp[b] = excl; rp[b+1] = excl+a0; rp[b+2] = excl+a0+a1; rp[b+3] = excl+a0+a1+a2;
    if (t == 1023) rp[4096] = s[1023];
}
__global__ __launch_bounds__(256) void k_fillcsr(const int* rpI, const int* rpJ, int* fI, int* fJ,
                                                 int* lI, int* lJ, const int* ei, const int* ej){
    int e = blockIdx.x*256 + threadIdx.x;
    if (e >= Ne) return;
    int i = ei[e], j = ej[e];
    lI[rpI[i] + atomicAdd(&fI[i], 1)] = e;
    lJ[rpJ[j] + atomicAdd(&fJ[j], 1)] = e;
}

// ---------------- split precompute ----------------
__global__ __launch_bounds__(256) void k_split4(ushort4* hi, ushort4* lo, const float4* w, int n4){
    int i = blockIdx.x*256 + threadIdx.x;
    if (i >= n4) return;
    float4 v = w[i];
    ushort4 h, l;
    h.x = f2bf(v.x); l.x = f2bf(v.x - bfh(h.x));
    h.y = f2bf(v.y); l.y = f2bf(v.y - bfh(h.y));
    h.z = f2bf(v.z); l.z = f2bf(v.z - bfh(h.z));
    h.w = f2bf(v.w); l.w = f2bf(v.w - bfh(h.w));
    hi[i] = h; lo[i] = l;
}
// fused mEA (row-major) + mEA^T split — r6 scalar version (HBM-roofline, 0 conflicts)
__global__ __launch_bounds__(256) void k_splitME2(u16* meh, u16* mel, u16* mth, u16* mtl,
                                                  const float* ea, const float* w22){
    __shared__ float T[64][65];
    int r0 = blockIdx.y*64, c0 = blockIdx.x*64;
    int c = threadIdx.x & 63, rr = threadIdx.x >> 6;
    for (int q = 0; q < 16; ++q){
        int r = q*4 + rr;
        size_t idx = (size_t)(r0+r)*Nn + c0 + c;
        float v = 0.5f*ea[idx]*w22[idx];
        T[r][c] = v;
        u16 h = f2bf(v); meh[idx] = h; mel[idx] = f2bf(v - bfh(h));
    }
    __syncthreads();
    for (int q = 0; q < 16; ++q){
        int r = q*4 + rr;
        float v = T[c][r];
        size_t o = (size_t)(c0+r)*Nn + r0 + c;
        u16 h = f2bf(v); mth[o] = h; mtl[o] = f2bf(v - bfh(h));
    }
}
// X [4096][256] f32 -> X^T split [256][4096]
__global__ __launch_bounds__(256) void k_splitXT(u16* hi, u16* lo, const float* X){
    __shared__ float T[64][65];
    int r0 = blockIdx.y*64, c0 = blockIdx.x*64;
    int c = threadIdx.x & 63, rr = threadIdx.x >> 6;
    for (int q = 0; q < 16; ++q){
        int r = q*4 + rr;
        T[r][c] = X[(size_t)(r0+r)*Ff + c0 + c];
    }
    __syncthreads();
    for (int q = 0; q < 16; ++q){
        int r = q*4 + rr;
        float v = T[c][r];
        size_t o = (size_t)(c0+r)*Nn + r0 + c;
        u16 h = f2bf(v); hi[o] = h; lo[o] = f2bf(v - bfh(h));
    }
}
// sum 16 G-planes (base 0) -> G^T split
__global__ __launch_bounds__(256) void k_splitGT(u16* hi, u16* lo, const float* Gp){
    __shared__ float T[64][65];
    int r0 = blockIdx.y*64, c0 = blockIdx.x*64;
    int c = threadIdx.x & 63, rr = threadIdx.x >> 6;
    for (int q = 0; q < 16; ++q){
        int r = q*4 + rr;
        float v = 0.f;
        #pragma unroll
        for (int z = 0; z < 16; ++z) v += Gp[z*(Ff*Ff) + (r0+r)*Ff + c0 + c];
        T[r][c] = v;
    }
    __syncthreads();
    for (int q = 0; q < 16; ++q){
        int r = q*4 + rr;
        float v = T[c][r];
        int o = (c0+r)*Ff + r0 + c;
        u16 h = f2bf(v); hi[o] = h; lo[o] = f2bf(v - bfh(h));
    }
}
// batched: z=0 -> planes 0..15 -> (h0,l0); z=1 -> planes 16..31 -> (h1,l1)
__global__ __launch_bounds__(256) void k_splitGT2(u16* h0, u16* l0, u16* h1, u16* l1,
                                                  const float* Gp){
    __shared__ float T[64][65];
    const int which = blockIdx.z;
    u16* hi = which ? h1 : h0;
    u16* lo = which ? l1 : l0;
    const float* G = Gp + (size_t)which*16*(Ff*Ff);
    int r0 = blockIdx.y*64, c0 = blockIdx.x*64;
    int c = threadIdx.x & 63, rr = threadIdx.x >> 6;
    for (int q = 0; q < 16; ++q){
        int r = q*4 + rr;
        float v = 0.f;
        #pragma unroll
        for (int z = 0; z < 16; ++z) v += G[z*(Ff*Ff) + (r0+r)*Ff + c0 + c];
        T[r][c] = v;
    }
    __syncthreads();
    for (int q = 0; q < 16; ++q){
        int r = q*4 + rr;
        float v = T[c][r];
        int o = (c0+r)*Ff + r0 + c;
        u16 h = f2bf(v); hi[o] = h; lo[o] = f2bf(v - bfh(h));
    }
}

// ---------------- small-GEMM MFMA tile core (verified r5-r15) ----------------
__device__ __forceinline__ void mm_tile(
    const u16* __restrict__ Ahp, const u16* __restrict__ Alp,
    const u16* __restrict__ Bhp, const u16* __restrict__ Blp,
    size_t sA, size_t sB, int i0, int j0, int k0,
    u16* LAh, u16* LAl, u16* LBh, u16* LBl,
    float4v* acc, int lane, int w)
{
    const int g1 = w*64 + lane;
    const int g2 = g1 + 256;
    const int r1 = g1>>3, p1 = g1&7, r2 = g2>>3, p2 = g2&7;
    const size_t a1 = (size_t)(i0+r1)*sA + (size_t)(k0 + ((p1 ^ (r1&7))<<3));
    const size_t a2 = (size_t)(i0+r2)*sA + (size_t)(k0 + ((p2 ^ (r2&7))<<3));
    const size_t b1 = (size_t)(j0+r1)*sB + (size_t)(k0 + ((p1 ^ (r1&7))<<3));
    const size_t b2 = (size_t)(j0+r2)*sB + (size_t)(k0 + ((p2 ^ (r2&7))<<3));
    __syncthreads();
    gload16(Ahp + a1, LAh + g1*8);
    gload16(Ahp + a2, LAh + g2*8);
    gload16(Alp + a1, LAl + g1*8);
    gload16(Alp + a2, LAl + g2*8);
    gload16(Bhp + b1, LBh + g1*8);
    gload16(Bhp + b2, LBh + g2*8);
    gload16(Blp + b1, LBl + g1*8);
    gload16(Blp + b2, LBl + g2*8);
    __syncthreads();
    const int arow = w*16 + (lane&15);
    const int aswz = arow & 7;
    #pragma unroll
    for (int kk = 0; kk < 2; ++kk){
        const int ch = kk*4 + (lane>>4);
        short8 ah = *(const short8*)(LAh + arow*64 + ((ch ^ aswz)<<3));
        short8 al = *(const short8*)(LAl + arow*64 + ((ch ^ aswz)<<3));
        #pragma unroll
        for (int c = 0; c < 4; ++c){
            const int brow = c*16 + (lane&15);
            const int bo = brow*64 + ((ch ^ (brow&7))<<3);
            short8 bh = *(const short8*)(LBh + bo);
            short8 bl = *(const short8*)(LBl + bo);
            acc[c] = __builtin_amdgcn_mfma_f32_16x16x32_bf16(ah, bh, acc[c], 0,0,0);
            acc[c] = __builtin_amdgcn_mfma_f32_16x16x32_bf16(ah, bl, acc[c], 0,0,0);
            acc[c] = __builtin_amdgcn_mfma_f32_16x16x32_bf16(al, bh, acc[c], 0,0,0);
        }
    }
}

// small GEMM (K=256): V4: out=aux[col]-acc  V5: out=acc
template<int V>
__global__ __launch_bounds__(256) void k_mm(float* __restrict__ out,
        const u16* __restrict__ Ahp, const u16* __restrict__ Alp,
        const u16* __restrict__ Bhp, const u16* __restrict__ Blp,
        const float* __restrict__ aux1){
    __shared__ u16 LAh[4096], LAl[4096], LBh[4096], LBl[4096];
    const int tid = threadIdx.x, lane = tid & 63, w = tid >> 6;
    const int j0 = blockIdx.x*64, i0 = blockIdx.y*64;
    float4v acc[4];
    #pragma unroll
    for (int c = 0; c < 4; ++c) acc[c] = (float4v){0.f,0.f,0.f,0.f};
    for (int kt = 0; kt < 4; ++kt)
        mm_tile(Ahp, Alp, Bhp, Blp, (size_t)Ff, (size_t)Ff, i0, j0, kt*64, LAh, LAl, LBh, LBl, acc, lane, w);
    #pragma unroll
    for (int c = 0; c < 4; ++c)
        #pragma unroll
        for (int r = 0; r < 4; ++r){
            int grow = i0 + w*16 + (lane>>4)*4 + r;
            int gcol = j0 + c*16 + (lane&15);
            size_t idx = (size_t)grow*Ff + gcol;
            float v = acc[c][r];
            if constexpr (V == 4) out[idx] = aux1[gcol] - v;
            if constexpr (V == 5) out[idx] = v;
        }
}

// batched plane-writing small GEMM: z=0: plane12 = A0@B0 ; z=1: plane13 = A1@B1
__global__ __launch_bounds__(256) void k_mmP(float* __restrict__ pb,
        const u16* __restrict__ A0h, const u16* __restrict__ A0l,
        const u16* __restrict__ B0h, const u16* __restrict__ B0l,
        const u16* __restrict__ A1h, const u16* __restrict__ A1l,
        const u16* __restrict__ B1h, const u16* __restrict__ B1l){
    __shared__ u16 LAh[4096], LAl[4096], LBh[4096], LBl[4096];
    const int tid = threadIdx.x, lane = tid & 63, w = tid >> 6;
    const int j0 = blockIdx.x*64, i0 = blockIdx.y*64, bat = blockIdx.z;
    const u16 *Ah = bat ? A1h : A0h;
    const u16 *Al = bat ? A1l : A0l;
    const u16 *Bh = bat ? B1h : B0h;
    const u16 *Bl = bat ? B1l : B0l;
    float4v acc[4];
    #pragma unroll
    for (int c = 0; c < 4; ++c) acc[c] = (float4v){0.f,0.f,0.f,0.f};
    for (int kt = 0; kt < 4; ++kt)
        mm_tile(Ah, Al, Bh, Bl, (size_t)Ff, (size_t)Ff, i0, j0, kt*64, LAh, LAl, LBh, LBl, acc, lane, w);
    float* op = pb + (size_t)(12 + bat)*NF;
    #pragma unroll
    for (int c = 0; c < 4; ++c)
        #pragma unroll
        for (int r = 0; r < 4; ++r){
            int grow = i0 + w*16 + (lane>>4)*4 + r;
            int gcol = j0 + c*16 + (lane&15);
            op[(size_t)grow*Ff + gcol] = acc[c][r];
        }
}

// Gram GEMM (single): Gp[z] = partial over K-chunk
__global__ __launch_bounds__(256) void k_gram_mm(float* __restrict__ Gp,
        const u16* __restrict__ Ahp, const u16* __restrict__ Alp,
        const u16* __restrict__ Bhp, const u16* __restrict__ Blp){
    __shared__ u16 LAh[4096], LAl[4096], LBh[4096], LBl[4096];
    const int tid = threadIdx.x, lane = tid & 63, w = tid >> 6;
    const int j0 = blockIdx.x*64, i0 = blockIdx.y*64, kb = blockIdx.z*256;
    float4v acc[4];
    #pragma unroll
    for (int c = 0; c < 4; ++c) acc[c] = (float4v){0.f,0.f,0.f,0.f};
    for (int kt = 0; kt < 4; ++kt)
        mm_tile(Ahp, Alp, Bhp, Blp, (size_t)Nn, (size_t)Nn, i0, j0, kb + kt*64, LAh, LAl, LBh, LBl, acc, lane, w);
    float* op = Gp + (size_t)blockIdx.z*(Ff*Ff);
    #pragma unroll
    for (int c = 0; c < 4; ++c)
        #pragma unroll
        for (int r = 0; r < 4; ++r){
            int grow = i0 + w*16 + (lane>>4)*4 + r;
            int gcol = j0 + c*16 + (lane&15);
            op[grow*Ff + gcol] = acc[c][r];
        }
}

// Batched Gram: z=0..15 -> (A,B) pair [y_old^T y_new]; z=16..31 -> (B,B) [y_new^T y_new]
__global__ __launch_bounds__(256) void k_gram_mm2(float* __restrict__ Gp,
        const u16* __restrict__ Ahp, const u16* __restrict__ Alp,
        const u16* __restrict__ Bhp, const u16* __restrict__ Blp){
    __shared__ u16 LAh[4096], LAl[4096], LBh[4096], LBl[4096];
    const int tid = threadIdx.x, lane = tid & 63, w = tid >> 6;
    const int j0 = blockIdx.x*64, i0 = blockIdx.y*64;
    const int pz = blockIdx.z;
    const int kb = (pz & 15)*256, which = pz >> 4;
    const u16* pAh = which ? Bhp : Ahp;
    const u16* pAl = which ? Blp : Alp;
    float4v acc[4];
    #pragma unroll
    for (int c = 0; c < 4; ++c) acc[c] = (float4v){0.f,0.f,0.f,0.f};
    for (int kt = 0; kt < 4; ++kt)
        mm_tile(pAh, pAl, Bhp, Blp, (size_t)Nn, (size_t)Nn, i0, j0, kb + kt*64, LAh, LAl, LBh, LBl, acc, lane, w);
    float* op = Gp + (size_t)pz*(Ff*Ff);
    #pragma unroll
    for (int c = 0; c < 4; ++c)
        #pragma unroll
        for (int r = 0; r < 4; ++r){
            int grow = i0 + w*16 + (lane>>4)*4 + r;
            int gcol = j0 + c*16 + (lane&15);
            op[grow*Ff + gcol] = acc[c][r];
        }
}

// ---------------- big GEMM (r12-verified core, templated K-split) ----------------
// BM=64, BN=256, BK=64, 512 thr, 80 KB LDS -> 2 blocks/CU.
// grid: (KSP, 64, nb): x = K-plane, y = i-block, z = batch. 64/KSP kt per block.
template<int KSP>
__global__ __launch_bounds__(512) void k_mmB(float* __restrict__ pb,
        const u16* __restrict__ A0h, const u16* __restrict__ A0l,
        const u16* __restrict__ B0h, const u16* __restrict__ B0l,
        const u16* __restrict__ A1h, const u16* __restrict__ A1l,
        const u16* __restrict__ B1h, const u16* __restrict__ B1l,
        const u16* __restrict__ A2h, const u16* __restrict__ A2l,
        const u16* __restrict__ B2h, const u16* __restrict__ B2l){
    __shared__ u16 LAh[4096], LAl[4096], LBh[16384], LBl[16384];
    const int tid = threadIdx.x, lane = tid & 63, w = tid >> 6;
    const int z = blockIdx.x, i0 = blockIdx.y*64, bat = blockIdx.z;
    const u16 *Ah, *Al, *Bh, *Bl;
    if (bat == 0){ Ah = A0h; Al = A0l; Bh = B0h; Bl = B0l; }
    else if (bat == 1){ Ah = A1h; Al = A1l; Bh = B1h; Bl = B1l; }
    else { Ah = A2h; Al = A2l; Bh = B2h; Bl = B2l; }
    const int wr = w >> 2, wc = w & 3;
    float4v acc[2][4];
    #pragma unroll
    for (int m = 0; m < 2; ++m)
        #pragma unroll
        for (int n = 0; n < 4; ++n) acc[m][n] = (float4v){0.f,0.f,0.f,0.f};

    const int ra = tid >> 3, pa = tid & 7;
    const size_t aoff = (size_t)(i0+ra)*Nn + (size_t)((pa ^ (ra&7))<<3);
    constexpr int NKT = 64 / KSP;

    for (int kt = 0; kt < NKT; ++kt){
        const int k0 = z*(NKT*64) + kt*64;
        __syncthreads();
        gload16(Ah + aoff + k0, LAh + tid*8);
        gload16(Al + aoff + k0, LAl + tid*8);
        #pragma unroll
        for (int it = 0; it < 4; ++it){
            int g = it*512 + tid;
            int r = g >> 3, p = g & 7;
            size_t b = (size_t)r*Nn + (size_t)(k0 + ((p ^ (r&7))<<3));
            gload16(Bh + b, LBh + g*8);
            gload16(Bl + b, LBl + g*8);
        }
        __syncthreads();
        #pragma unroll
        for (int kk = 0; kk < 2; ++kk){
            const int ch = kk*4 + (lane>>4);
            short8 ah0, ah1, al0, al1;
            {
                const int arow = wr*32 + (lane&15);
                const int ao = arow*64 + ((ch ^ (arow&7))<<3);
                ah0 = *(const short8*)(LAh + ao);
                al0 = *(const short8*)(LAl + ao);
            }
            {
                const int arow = wr*32 + 16 + (lane&15);
                const int ao = arow*64 + ((ch ^ (arow&7))<<3);
                ah1 = *(const short8*)(LAh + ao);
                al1 = *(const short8*)(LAl + ao);
            }
            #pragma unroll
            for (int n = 0; n < 4; ++n){
                const int bcol = wc*64 + n*16 + (lane&15);
                const int bo = bcol*64 + ((ch ^ (bcol&7))<<3);
                short8 bh = *(const short8*)(LBh + bo);
                short8 bl = *(const short8*)(LBl + bo);
                acc[0][n] = __builtin_amdgcn_mfma_f32_16x16x32_bf16(ah0, bh, acc[0][n], 0,0,0);
                acc[0][n] = __builtin_amdgcn_mfma_f32_16x16x32_bf16(ah0, bl, acc[0][n], 0,0,0);
                acc[0][n] = __builtin_amdgcn_mfma_f32_16x16x32_bf16(al0, bh, acc[0][n], 0,0,0);
                acc[1][n] = __builtin_amdgcn_mfma_f32_16x16x32_bf16(ah1, bh, acc[1][n], 0,0,0);
                acc[1][n] = __builtin_amdgcn_mfma_f32_16x16x32_bf16(ah1, bl, acc[1][n], 0,0,0);
                acc[1][n] = __builtin_amdgcn_mfma_f32_16x16x32_bf16(al1, bh, acc[1][n], 0,0,0);
            }
        }
    }
    float* op = pb + ((size_t)bat*KSP + z)*NF;
    #pragma unroll
    for (int m = 0; m < 2; ++m)
        #pragma unroll
        for (int n = 0; n < 4; ++n)
            #pragma unroll
            for (int r = 0; r < 4; ++r){
                int row = i0 + wr*32 + m*16 + (lane>>4)*4 + r;
                int col = wc*64 + n*16 + (lane&15);
                op[(size_t)row*Ff + col] = acc[m][n][r];
            }
}

// t1 final reduce: t1 += sum(pb[0..3]) - (HASM? sum(pb[8..11]) : 0)
//                  (+ PL1213? pb[12] - pb[13] : 0); transpose-split to th/tl
template<int HASM, int PL1213>
__global__ __launch_bounds__(256) void k_redT1(float* __restrict__ t1, const float* __restrict__ pb,
        u16* __restrict__ th, u16* __restrict__ tl){
    __shared__ float T[64][65];
    const int c0 = blockIdx.x*64, r0 = blockIdx.y*64;
    const int c = threadIdx.x & 63, rr = threadIdx.x >> 6;
    for (int q = 0; q < 16; ++q){
        int row = q*4 + rr;
        size_t idx = (size_t)(r0+row)*Ff + c0 + c;
        float s = 0.f;
        #pragma unroll
        for (int p = 0; p < 4; ++p) s += pb[(size_t)p*NF + idx];
        if constexpr (HASM){
            #pragma unroll
            for (int p = 0; p < 4; ++p) s -= pb[((size_t)8 + p)*NF + idx];
        }
        if constexpr (PL1213)
            s += pb[(size_t)12*NF + idx] - pb[(size_t)13*NF + idx];
        float val = t1[idx] + s;
        t1[idx] = val;
        T[row][c] = val;
    }
    __syncthreads();
    for (int q = 0; q < 16; ++q){
        int r = q*4 + rr;
        float v = T[c][r];
        size_t o = (size_t)(c0+r)*Nn + r0 + c;
        u16 h = f2bf(v); th[o] = h; tl[o] = f2bf(v - bfh(h));
    }
}

// yn epilogue (w1 uses KSP=8): yn = feat + 0.5*sigmoid(sum(pb[0..7])); row + transpose splits
__global__ __launch_bounds__(256) void k_redY(float* __restrict__ yn, const float* __restrict__ pb,
        const float* __restrict__ feat, u16* __restrict__ rh, u16* __restrict__ rl,
        u16* __restrict__ th, u16* __restrict__ tl){
    __shared__ float T[64][65];
    const int c0 = blockIdx.x*64, r0 = blockIdx.y*64;
    const int c = threadIdx.x & 63, rr = threadIdx.x >> 6;
    for (int q = 0; q < 16; ++q){
        int row = q*4 + rr;
        size_t idx = (size_t)(r0+row)*Ff + c0 + c;
        float s = 0.f;
        #pragma unroll
        for (int p = 0; p < 8; ++p) s += pb[(size_t)p*NF + idx];
        float val = feat[idx] + 0.5f*(1.f/(1.f+expf(-s)));
        yn[idx] = val;
        u16 h = f2bf(val); rh[idx] = h; rl[idx] = f2bf(val - bfh(h));
        T[row][c] = val;
    }
    __syncthreads();
    for (int q = 0; q < 16; ++q){
        int r = q*4 + rr;
        float v = T[c][r];
        size_t o = (size_t)(c0+r)*Nn + r0 + c;
        u16 h = f2bf(v); th[o] = h; tl[o] = f2bf(v - bfh(h));
    }
}

// ---------------- fused CSR sparse + z dense (pb1 = 4 planes) ----------------
// ADDBASE=1: t1 += sparse (t=1, base pre-written); ADDBASE=0: t1 = sparse (t>=2)
template<int ADDBASE>
__global__ __launch_bounds__(256) void k_csrTZ(float* __restrict__ t1, float* __restrict__ zn,
        const float* __restrict__ y, const float* __restrict__ z, const float* __restrict__ pb1,
        const float* __restrict__ cc, const float* __restrict__ P,
        const int* __restrict__ rpI, const int* __restrict__ lI, const int* __restrict__ ej,
        const int* __restrict__ rpJ, const int* __restrict__ lJ, const int* __restrict__ ei,
        int useM){
    const int r = blockIdx.x, f = threadIdx.x;
    float at = 0.f, az = 0.f;
    const int b0 = rpI[r], b1 = rpI[r+1];
    for (int p = b0; p < b1; ++p){
        int e = lI[p];
        float ce = cc[e];
        int j = ej[e];
        at += ce * y[(size_t)j*Ff + f];
        az += ce * z[(size_t)j*Ff + f];
    }
    if (useM){
        const int c0 = rpJ[r], c1 = rpJ[r+1];
        for (int p = c0; p < c1; ++p){
            int e = lJ[p];
            at -= 0.5f * P[e] * y[(size_t)ei[e]*Ff + f];
        }
    }
    size_t idx = (size_t)r*Ff + f;
    float dz = 0.f;
    #pragma unroll
    for (int p = 0; p < 4; ++p) dz += pb1[(size_t)p*NF + idx];
    if constexpr (ADDBASE) t1[idx] += at;
    else                   t1[idx] = at;
    zn[idx] = z[idx] - dz - az;
}

__global__ __launch_bounds__(256) void k_colsum(float* col, const float* __restrict__ y){
    int j = threadIdx.x;
    int r0 = blockIdx.x*64;
    float s = 0.f;
    for (int i = 0; i < 64; ++i) s += y[(size_t)(r0+i)*Ff + j];
    atomicAdd(&col[j], s);
}

// ---------------- per-edge kernels ----------------
__global__ __launch_bounds__(256) void k_pacc(float* __restrict__ P, float* __restrict__ hV,
        const float* __restrict__ z, const int* __restrict__ ei, const int* __restrict__ ej,
        const float* __restrict__ ev, const u32* __restrict__ slot){
    int e = blockIdx.x*4 + (threadIdx.x >> 6);
    int lane = threadIdx.x & 63;
    int i = ei[e], j = ej[e];
    float s = 0.f;
    #pragma unroll
    for (int q = 0; q < 4; ++q){
        int f = lane + q*64;
        float d = z[(size_t)i*Ff + f] - z[(size_t)j*Ff + f];
        s += d*d;
    }
    #pragma unroll
    for (int o = 32; o; o >>= 1) s += __shfl_xor(s, o);
    if (lane == 0){
        float v = sqrtf(s) * ev[e];
        P[e] = v;
        atomicAdd(&hV[slot[e]], v);
    }
}
__global__ __launch_bounds__(256) void k_ep(float* __restrict__ c, const float* __restrict__ y,
        const int* __restrict__ ei, const int* __restrict__ ej, const float* __restrict__ ev,
        const float* __restrict__ V, const u32* __restrict__ slot){
    int e = blockIdx.x*4 + (threadIdx.x >> 6);
    int lane = threadIdx.x & 63;
    int i = ei[e], j = ej[e];
    float s = 0.f;
    #pragma unroll
    for (int q = 0; q < 4; ++q){
        int f = lane + q*64;
        s += y[(size_t)i*Ff + f] * y[(size_t)j*Ff + f];
    }
    #pragma unroll
    for (int o = 32; o; o >>= 1) s += __shfl_xor(s, o);
    if (lane == 0) c[e] = ev[e] * (s - 0.5f * V[slot[e]]);
}

// ---------------- head ----------------
__global__ __launch_bounds__(256) void k_head(float* __restrict__ out, const float* __restrict__ y,
                                              const float* __restrict__ z, const float* __restrict__ w2w,
                                              const float* __restrict__ w2b){
    const int node = blockIdx.x, t = threadIdx.x;
    float yv = y[(size_t)node*Ff + t], zv = z[(size_t)node*Ff + t];
    float yc = fminf(fmaxf(yv, -1e37f), 1e37f);
    float zc = fminf(fmaxf(zv, -1e37f), 1e37f);
    __shared__ float sy[256], sz[256];
    sy[t] = fabsf(yc); sz[t] = fabsf(zc);
    __syncthreads();
    for (int s = 128; s; s >>= 1){ if (t < s){ sy[t]=fmaxf(sy[t],sy[t+s]); sz[t]=fmaxf(sz[t],sz[t+s]); } __syncthreads(); }
    float my_ = fmaxf(sy[0], 1e-30f), mz_ = fmaxf(sz[0], 1e-30f);
    __syncthreads();
    float ysc = yc/my_, zsc = zc/mz_;
    sy[t] = ysc*ysc; sz[t] = zsc*zsc;
    __syncthreads();
    for (int s = 128; s; s >>= 1){ if (t < s){ sy[t]+=sy[t+s]; sz[t]+=sz[t+s]; } __syncthreads(); }
    float ny = fmaxf(my_*sqrtf(sy[0]), 1e-12f);
    float nz = fmaxf(mz_*sqrtf(sz[0]), 1e-12f);
    float ynv = yc/ny, znv = zc/nz;
    float acc[NCLS];
    #pragma unroll
    for (int cc = 0; cc < NCLS; ++cc)
        acc[cc] = znv*w2w[t*NCLS+cc] + ynv*w2w[(Ff+t)*NCLS+cc];
    __shared__ float red[NCLS][257];
    #pragma unroll
    for (int cc = 0; cc < NCLS; ++cc) red[cc][t] = acc[cc];
    __syncthreads();
    for (int s = 128; s; s >>= 1){
        if (t < s){
            #pragma unroll
            for (int cc = 0; cc < NCLS; ++cc) red[cc][t] += red[cc][t+s];
        }
        __syncthreads();
    }
    __shared__ float lg[NCLS];
    __shared__ float ml[2];
    if (t < NCLS) lg[t] = red[t][0] + w2b[t];
    __syncthreads();
    if (t == 0){
        float m = -1e30f;
        for (int cc = 0; cc < NCLS; ++cc) m = fmaxf(m, lg[cc]);
        float se = 0.f;
        for (int cc = 0; cc < NCLS; ++cc) se += expf(lg[cc]-m);
        ml[0] = m; ml[1] = logf(se);
    }
    __syncthreads();
    if (t < NCLS) out[(size_t)node*NCLS + t] = lg[t] - ml[0] - ml[1];
}

extern "C" void kernel_launch(void* const* d_in, const int* in_sizes, int n_in,
                              void* d_out, int out_size, void* d_ws, size_t ws_size,
                              hipStream_t stream){
    const float* feat = (const float*)d_in[0];
    const float* z0i  = (const float*)d_in[1];
    const float* w1p  = (const float*)d_in[2];
    const float* EAp  = (const float*)d_in[3];
    const float* w2w  = (const float*)d_in[4];
    const float* w2b  = (const float*)d_in[5];
    const float* w22p = (const float*)d_in[7];
    const float* evp  = (const float*)d_in[8];
    const int* ei   = (const int*)d_in[9];
    const int* ej   = (const int*)d_in[10];
    float* out = (float*)d_out;

    int ok = (n_in == 11) && (out_size == Nn*NCLS)
           && in_sizes[0]==NF && in_sizes[1]==NF && in_sizes[2]==NNx && in_sizes[3]==NNx
           && in_sizes[4]==2*Ff*NCLS && in_sizes[5]==NCLS && in_sizes[6]==NNx && in_sizes[7]==NNx
           && in_sizes[8]==Ne && in_sizes[9]==Ne && in_sizes[10]==Ne;
    if (!ok){
        k_fillc<<<(out_size+255)/256, 256, 0, stream>>>(out, -100.0f, out_size);
        return;
    }

    float *yA,*yB,*zA,*zB,*t1,*T1,*Gp,*col,*P,*cc,*hV,*pb; u32 *hK,*slot;
    int *cntI,*cntJ,*rpI,*rpJ,*fI,*fJ,*lI,*lJ;
    u16 *w1h,*w1l,*meh,*mel,*mth,*mtl,*gth,*gtl,*g2h,*g2l,*tth,*ttl;
    u16 *xh[2],*xl[2],*zth[2],*ztl[2],*yrh[2],*yrl[2];
    hipGetSymbolAddress((void**)&yA,  HIP_SYMBOL(g_yA));
    hipGetSymbolAddress((void**)&yB,  HIP_SYMBOL(g_yB));
    hipGetSymbolAddress((void**)&zA,  HIP_SYMBOL(g_zA));
    hipGetSymbolAddress((void**)&zB,  HIP_SYMBOL(g_zB));
    hipGetSymbolAddress((void**)&t1,  HIP_SYMBOL(g_t1));
    hipGetSymbolAddress((void**)&T1,  HIP_SYMBOL(g_T1));
    hipGetSymbolAddress((void**)&Gp,  HIP_SYMBOL(g_Gp));
    hipGetSymbolAddress((void**)&col, HIP_SYMBOL(g_col));
    hipGetSymbolAddress((void**)&P,   HIP_SYMBOL(g_P));
    hipGetSymbolAddress((void**)&cc,  HIP_SYMBOL(g_cc));
    hipGetSymbolAddress((void**)&hV,  HIP_SYMBOL(g_hV));
    hipGetSymbolAddress((void**)&pb,  HIP_SYMBOL(g_pb));
    hipGetSymbolAddress((void**)&hK,  HIP_SYMBOL(g_hK));
    hipGetSymbolAddress((void**)&slot,HIP_SYMBOL(g_slot));
    hipGetSymbolAddress((void**)&cntI,HIP_SYMBOL(g_cntI));
    hipGetSymbolAddress((void**)&cntJ,HIP_SYMBOL(g_cntJ));
    hipGetSymbolAddress((void**)&rpI, HIP_SYMBOL(g_rpI));
    hipGetSymbolAddress((void**)&rpJ, HIP_SYMBOL(g_rpJ));
    hipGetSymbolAddress((void**)&fI,  HIP_SYMBOL(g_fI));
    hipGetSymbolAddress((void**)&fJ,  HIP_SYMBOL(g_fJ));
    hipGetSymbolAddress((void**)&lI,  HIP_SYMBOL(g_lI));
    hipGetSymbolAddress((void**)&lJ,  HIP_SYMBOL(g_lJ));
    hipGetSymbolAddress((void**)&w1h, HIP_SYMBOL(g_w1h));
    hipGetSymbolAddress((void**)&w1l, HIP_SYMBOL(g_w1l));
    hipGetSymbolAddress((void**)&meh, HIP_SYMBOL(g_meh));
    hipGetSymbolAddress((void**)&mel, HIP_SYMBOL(g_mel));
    hipGetSymbolAddress((void**)&mth, HIP_SYMBOL(g_mth));
    hipGetSymbolAddress((void**)&mtl, HIP_SYMBOL(g_mtl));
    hipGetSymbolAddress((void**)&gth, HIP_SYMBOL(g_gth));
    hipGetSymbolAddress((void**)&gtl, HIP_SYMBOL(g_gtl));
    hipGetSymbolAddress((void**)&g2h, HIP_SYMBOL(g_g2h));
    hipGetSymbolAddress((void**)&g2l, HIP_SYMBOL(g_g2l));
    hipGetSymbolAddress((void**)&tth, HIP_SYMBOL(g_tth));
    hipGetSymbolAddress((void**)&ttl, HIP_SYMBOL(g_ttl));
    hipGetSymbolAddress((void**)&xh[0], HIP_SYMBOL(g_x0h));
    hipGetSymbolAddress((void**)&xl[0], HIP_SYMBOL(g_x0l));
    hipGetSymbolAddress((void**)&xh[1], HIP_SYMBOL(g_x1h));
    hipGetSymbolAddress((void**)&xl[1], HIP_SYMBOL(g_x1l));
    hipGetSymbolAddress((void**)&zth[0], HIP_SYMBOL(g_zt0h));
    hipGetSymbolAddress((void**)&ztl[0], HIP_SYMBOL(g_zt0l));
    hipGetSymbolAddress((void**)&zth[1], HIP_SYMBOL(g_zt1h));
    hipGetSymbolAddress((void**)&ztl[1], HIP_SYMBOL(g_zt1l));
    hipGetSymbolAddress((void**)&yrh[0], HIP_SYMBOL(g_yr0h));
    hipGetSymbolAddress((void**)&yrl[0], HIP_SYMBOL(g_yr0l));
    hipGetSymbolAddress((void**)&yrh[1], HIP_SYMBOL(g_yr1h));
    hipGetSymbolAddress((void**)&yrl[1], HIP_SYMBOL(g_yr1l));

    const dim3 gSmall(Ff/64, Nn/64);
    const dim3 gP(Ff/64, Nn/64, 2);
    const dim3 gXT(Ff/64, Nn/64);
    const dim3 gME(Nn/64, Nn/64);
    const dim3 gGT(Ff/64, Ff/64);
    const dim3 gGram(4, 4, 16);
    const dim3 gGram2(4, 4, 32);
    const dim3 gGT2(4, 4, 2);
    const dim3 gRed(Ff/64, Nn/64);

    // ---- startup ----
    k_split4<<<NNx/4/256, 256, 0, stream>>>((ushort4*)w1h, (ushort4*)w1l, (const float4*)w1p, NNx/4);
    k_splitME2<<<gME, 256, 0, stream>>>(meh, mel, mth, mtl, EAp, w22p);
    k_split4<<<NF/4/256, 256, 0, stream>>>((ushort4*)yrh[0], (ushort4*)yrl[0], (const float4*)feat, NF/4);
    k_splitXT<<<gXT, 256, 0, stream>>>(xh[0], xl[0], feat);
    k_splitXT<<<gXT, 256, 0, stream>>>(zth[0], ztl[0], z0i);
    k_hkeys_clear<<<TSZ/256, 256, 0, stream>>>(hK);
    k_hsetup<<<Ne/256, 256, 0, stream>>>(hK, slot, ei, ej);
    k_zeroi<<<Nn/256, 256, 0, stream>>>(cntI, Nn);
    k_zeroi<<<Nn/256, 256, 0, stream>>>(cntJ, Nn);
    k_count<<<Ne/256, 256, 0, stream>>>(cntI, cntJ, ei, ej);
    k_scan<<<1, 1024, 0, stream>>>(cntI, rpI);
    k_scan<<<1, 1024, 0, stream>>>(cntJ, rpJ);
    k_zeroi<<<Nn/256, 256, 0, stream>>>(fI, Nn);
    k_zeroi<<<Nn/256, 256, 0, stream>>>(fJ, Nn);
    k_fillcsr<<<Ne/256, 256, 0, stream>>>(rpI, rpJ, fI, fJ, lI, lJ, ei, ej);

    const float* yv = feat;  const float* zv = z0i;
    for (int t = 1; t <= 4; ++t){
        int ri = (t-1) & 1, wi = t & 1;
        u16 *xhc = xh[ri], *xlc = xl[ri], *xhn = xh[wi], *xln = xl[wi];
        u16 *zthc = zth[ri], *ztlc = ztl[ri], *zthn = zth[wi], *ztln = ztl[wi];
        u16 *yrhc = yrh[ri], *yrlc = yrl[ri], *yrhn = yrh[wi], *yrln = yrl[wi];
        float* yn = (t & 1) ? yA : yB;
        float* zn = (t & 1) ? zA : zB;
        const float* ccv = (t == 1) ? evp : cc;

        // 1+2. t1 base
        if (t == 1){
            // G = y0^T y0 -> split ; t1 = colsum - y0@G
            k_gram_mm<<<gGram, 256, 0, stream>>>(Gp, xhc, xlc, xhc, xlc);
            k_splitGT<<<gGT, 256, 0, stream>>>(gth, gtl, Gp);
            k_zero<<<1, 256, 0, stream>>>(col, Ff);
            k_colsum<<<64, 256, 0, stream>>>(col, yv);
            k_mm<4><<<gSmall, 256, 0, stream>>>(t1, yrhc, yrlc, gth, gtl, col);
        } else {
            // batched: plane12 = y_{t-2}@gth (T1 carry); plane13 = y_{t-1}@g2
            // (yr[wi] still holds y_{t-2}'s rows; gth/g2 from previous layer's splitGT2)
            k_mmP<<<gP, 256, 0, stream>>>(pb,
                yrh[wi], yrl[wi], gth, gtl,
                yrhc, yrlc, g2h, g2l);
        }
        // 3. batched dense GEMMs (KSP=4): b0 = mEA@y, b1 = mEA@z, b2 = mEA^T@y (t>=2)
        {
            int nb = (t == 1) ? 2 : 3;
            dim3 gB(4, Nn/64, nb);
            k_mmB<4><<<gB, 512, 0, stream>>>(pb,
                meh, mel, xhc, xlc,
                meh, mel, zthc, ztlc,
                mth, mtl, xhc, xlc);
        }
        // 4. fused sparse + z dense
        if (t == 1)
            k_csrTZ<1><<<Nn, 256, 0, stream>>>(t1, zn, yv, zv, pb + (size_t)4*NF, ccv, P,
                                               rpI, lI, ej, rpJ, lJ, ei, 0);
        else
            k_csrTZ<0><<<Nn, 256, 0, stream>>>(t1, zn, yv, zv, pb + (size_t)4*NF, ccv, P,
                                               rpI, lI, ej, rpJ, lJ, ei, 1);
        // 5. t1 final dense adds (+ plane12-13 base for t>=2) + transpose split
        if (t == 1) k_redT1<0,0><<<gRed, 256, 0, stream>>>(t1, pb, tth, ttl);
        else        k_redT1<1,1><<<gRed, 256, 0, stream>>>(t1, pb, tth, ttl);
        // 6. z^T split for next layer (post-sparse z)
        if (t < 4)
            k_splitXT<<<gXT, 256, 0, stream>>>(zthn, ztln, zn);
        // 7. yn = feat + 0.5*sigmoid(w1@t1) (KSP=8, 512 blocks = 2/CU)
        {
            dim3 gB(8, Nn/64, 1);
            k_mmB<8><<<gB, 512, 0, stream>>>(pb,
                w1h, w1l, tth, ttl,
                w1h, w1l, tth, ttl,
                w1h, w1l, tth, ttl);
        }
        k_redY<<<gRed, 256, 0, stream>>>(yn, pb, feat, yrhn, yrln, xhn, xln);
        // 8. next-layer EP coefficients + batched Grams (uses OLD y,z)
        if (t < 4){
            k_zero<<<TSZ/256, 256, 0, stream>>>(hV, TSZ);
            k_pacc<<<Ne/4, 256, 0, stream>>>(P, hV, zv, ei, ej, evp, slot);
            k_ep<<<Ne/4, 256, 0, stream>>>(cc, yv, ei, ej, evp, hV, slot);
            k_gram_mm2<<<gGram2, 256, 0, stream>>>(Gp, xhc, xlc, xhn, xln);   // [y^T yn | yn^T yn]
            k_splitGT2<<<gGT2, 256, 0, stream>>>(gth, gtl, g2h, g2l, Gp);
        }
        yv = yn; zv = zn;
    }
    k_head<<<Nn, 256, 0, stream>>>(out, yv, zv, w2w, w2b);
}